// Round 2
// baseline (2542.880 us; speedup 1.0000x reference)
//
#include <hip/hip_runtime.h>
#include <hip/hip_bf16.h>
#include <math.h>

#define N_NODES 50000
#define N_EDGES 500000
#define H 128
#define NL 3
#define SCAN_B 256
#define NCHUNK ((N_NODES + SCAN_B - 1) / SCAN_B)

typedef short short8v __attribute__((ext_vector_type(8)));
typedef float f32x4 __attribute__((ext_vector_type(4)));
typedef unsigned short ushort8v __attribute__((ext_vector_type(8)));
typedef unsigned short ushort4v __attribute__((ext_vector_type(4)));

__device__ __forceinline__ unsigned short f2b(float f) {
  __hip_bfloat16 h = __float2bfloat16(f);
  return __builtin_bit_cast(unsigned short, h);
}
__device__ __forceinline__ float b2f(unsigned short s) {
  unsigned u = (unsigned)s << 16;
  return __builtin_bit_cast(float, u);
}

// ---------------- counting sort of edges by dst ----------------

__global__ void k_deg_i(const int* __restrict__ dst, int* __restrict__ degC) {
  int e = blockIdx.x * blockDim.x + threadIdx.x;
  if (e < N_EDGES) atomicAdd(&degC[dst[e]], 1);
}

__global__ void k_inv(const int* __restrict__ degC, float* __restrict__ invd) {
  int i = blockIdx.x * blockDim.x + threadIdx.x;
  if (i < N_NODES) invd[i] = 1.0f / fmaxf((float)degC[i], 1.0f);
}

__global__ void k_scan1(const int* __restrict__ degC, int* __restrict__ cursor,
                        int* __restrict__ chunkSum) {
  __shared__ int s[SCAN_B];
  int t = threadIdx.x, i = blockIdx.x * SCAN_B + t;
  int v = (i < N_NODES) ? degC[i] : 0;
  s[t] = v;
  __syncthreads();
  for (int o = 1; o < SCAN_B; o <<= 1) {
    int u = (t >= o) ? s[t - o] : 0;
    __syncthreads();
    s[t] += u;
    __syncthreads();
  }
  if (i < N_NODES) cursor[i] = s[t] - v;
  if (t == SCAN_B - 1) chunkSum[blockIdx.x] = s[t];
}

__global__ void k_scan2(int* __restrict__ chunkSum) {
  __shared__ int s[SCAN_B];
  int t = threadIdx.x;
  int v = (t < NCHUNK) ? chunkSum[t] : 0;
  s[t] = v;
  __syncthreads();
  for (int o = 1; o < SCAN_B; o <<= 1) {
    int u = (t >= o) ? s[t - o] : 0;
    __syncthreads();
    s[t] += u;
    __syncthreads();
  }
  if (t < NCHUNK) chunkSum[t] = s[t] - v;
}

__global__ void k_scan3(int* __restrict__ cursor, const int* __restrict__ chunkSum) {
  int i = blockIdx.x * SCAN_B + threadIdx.x;
  if (i < N_NODES) cursor[i] += chunkSum[blockIdx.x];
}

__global__ void k_scatter_sort(const int* __restrict__ dst, int* __restrict__ cursor,
                               int* __restrict__ sorted) {
  int e = blockIdx.x * blockDim.x + threadIdx.x;
  if (e < N_EDGES) {
    int p = atomicAdd(&cursor[dst[e]], 1);
    sorted[p] = e;
  }
}

// ---------------- fp32 -> bf16 conversions ----------------

__global__ void k_cvt_x(const float* __restrict__ x, unsigned short* __restrict__ xb, int n4) {
  int i = blockIdx.x * blockDim.x + threadIdx.x;
  if (i < n4) {
    float4 v = ((const float4*)x)[i];
    ushort4v o;
    o[0] = f2b(v.x); o[1] = f2b(v.y); o[2] = f2b(v.z); o[3] = f2b(v.w);
    ((ushort4v*)xb)[i] = o;
  }
}

// src [L][K][N] fp32 -> dst [L][N][K] bf16
__global__ void k_cvt_wt(const float* __restrict__ src, unsigned short* __restrict__ dst,
                         int K, int N, int total) {
  int i = blockIdx.x * blockDim.x + threadIdx.x;
  if (i < total) {
    int l = i / (K * N);
    int rem = i - l * K * N;
    int k = rem / N;
    int n = rem - k * N;
    dst[((size_t)l * N + n) * K + k] = f2b(src[i]);
  }
}

// ---------------- MFMA helper: A from LDS, B direct from global [N][K] bf16 ----------------
// wave wv owns output rows wv*16..+15; 8 N-tiles of 16 cols.
// A fragment: row = wv*16 + (lane&15), k = AKOFF + ks*32 + quad*8 (8 contiguous bf16)
// B fragment: row n = nt*16 + (lane&15) of BP (pitch BPITCH), same k window (identical
//   addresses across the 4 waves -> L1 broadcast; weights are L2-resident)
// C/D: D[wv*16 + quad*4 + r][nt*16 + (lane&15)] = acc[nt][r]
#define MFMA_STEP_G(AP, APITCH, AKOFF, BP, BPITCH, BKOFF, ACCN)                    \
  { _Pragma("unroll")                                                              \
    for (int ks_ = 0; ks_ < 2; ++ks_) {                                            \
      short8v af_ = *(const short8v*)&AP[(wv * 16 + ln15) * (APITCH) + (AKOFF) + ks_ * 32 + quad * 8]; \
      _Pragma("unroll")                                                            \
      for (int nt_ = 0; nt_ < 8; ++nt_) {                                          \
        short8v bf_ = *(const short8v*)&BP[(size_t)(nt_ * 16 + ln15) * (BPITCH) + (BKOFF) + ks_ * 32 + quad * 8]; \
        ACCN[nt_] = __builtin_amdgcn_mfma_f32_16x16x32_bf16(af_, bf_, ACCN[nt_], 0, 0, 0); \
      } } }

// ---------------- per-layer node-side precompute: XAB = x @ [W1a|W1b] (+mb1 folded) ----
// out: xab [N_NODES][256] bf16, cols 0..127 = x@W1a + mb1 (dst part), 128..255 = x@W1b

__launch_bounds__(256, 6)
__global__ void k_xab(const unsigned short* __restrict__ xb,
                      const unsigned short* __restrict__ mW1t,  // [128n][384k]
                      const float* __restrict__ mb1,
                      unsigned short* __restrict__ xab)
{
  const int tid = threadIdx.x;
  const int n0 = blockIdx.x * 64;
  const int wv = tid >> 6, lane = tid & 63, quad = lane >> 4, ln15 = lane & 15;
  const int arow = min(n0 + wv * 16 + ln15, N_NODES - 1);

  // A fragments (K=128 of this node row), reused across both output halves
  short8v afr[2][2];
#pragma unroll
  for (int c = 0; c < 2; ++c)
#pragma unroll
    for (int ks = 0; ks < 2; ++ks)
      afr[c][ks] = *(const short8v*)&xb[(size_t)arow * H + c * 64 + ks * 32 + quad * 8];

#pragma unroll
  for (int h = 0; h < 2; ++h) {
    f32x4 acc[8];
#pragma unroll
    for (int nt = 0; nt < 8; ++nt) acc[nt] = (f32x4){0.f, 0.f, 0.f, 0.f};
#pragma unroll
    for (int c = 0; c < 2; ++c)
#pragma unroll
      for (int ks = 0; ks < 2; ++ks)
#pragma unroll
        for (int nt = 0; nt < 8; ++nt) {
          short8v bf = *(const short8v*)&mW1t[(size_t)(nt * 16 + ln15) * 384 + h * 128 + c * 64 + ks * 32 + quad * 8];
          acc[nt] = __builtin_amdgcn_mfma_f32_16x16x32_bf16(afr[c][ks], bf, acc[nt], 0, 0, 0);
        }
#pragma unroll
    for (int nt = 0; nt < 8; ++nt) {
      int col = nt * 16 + ln15;
      float bb = (h == 0) ? mb1[col] : 0.f;
#pragma unroll
      for (int r = 0; r < 4; ++r) {
        int row = n0 + wv * 16 + quad * 4 + r;
        if (row < N_NODES)
          xab[(size_t)row * 256 + h * 128 + col] = f2b(acc[nt][r] + bb);
      }
    }
  }
}

// ---------------- fused edge kernel (bf16 MFMA, barrier-light) ----------------

__launch_bounds__(256, 6)
__global__ void k_edge(const unsigned short* __restrict__ xab,   // [N][256] bf16
                       const float* __restrict__ pos,
                       const float* __restrict__ eattr,
                       const int* __restrict__ srcI,
                       const int* __restrict__ dstI,
                       const int* __restrict__ sorted,
                       const unsigned short* __restrict__ mW1t,
                       const unsigned short* __restrict__ mW2t, const float* __restrict__ mb2,
                       const unsigned short* __restrict__ aW1t, const float* __restrict__ ab1,
                       const float* __restrict__ aW2, const float* __restrict__ ab2,
                       float* __restrict__ intra,
                       float* __restrict__ pdelta,
                       int do_intra)
{
  __shared__ unsigned short sM[64 * 136];   // XA+XB -> h1 -> m; [64][128] bf16, pitch 136
  __shared__ int sEid[64], sSrc[64], sDst[64];
  __shared__ float sW[64];
  __shared__ float sPE[64 * 3];

  const int tid = threadIdx.x;
  // bijective XCD-aware swizzle: consecutive dst-sorted tiles land on the same XCD
  const int nwg = gridDim.x;
  const int q_ = nwg >> 3, r_ = nwg & 7;
  const int xcd = blockIdx.x & 7, bidx = blockIdx.x >> 3;
  const int bid = (xcd < r_ ? xcd * (q_ + 1) : r_ * (q_ + 1) + (xcd - r_) * q_) + bidx;
  const int e0 = bid * 64;
  const int nv = min(N_EDGES - e0, 64);
  if (tid < 64) {
    int idx = min(e0 + tid, N_EDGES - 1);
    int eid = sorted[idx];
    sEid[tid] = eid; sSrc[tid] = srcI[eid]; sDst[tid] = dstI[eid];
  }
  __syncthreads();                                              // B1

  const int wv = tid >> 6, lane = tid & 63, quad = lane >> 4, ln15 = lane & 15;

  // ---- assemble XA[dst] + XB[src] (bias pre-folded) into sM ----
#pragma unroll
  for (int i_ = 0; i_ < 4; ++i_) {
    int flat = tid + i_ * 256;          // 0..1023 = 64 rows x 16 seg8
    int row = flat >> 4, sg = flat & 15;
    ushort8v a = *(const ushort8v*)&xab[(size_t)sDst[row] * 256 + sg * 8];
    ushort8v b = *(const ushort8v*)&xab[(size_t)sSrc[row] * 256 + 128 + sg * 8];
    ushort8v o;
#pragma unroll
    for (int j = 0; j < 8; ++j) o[j] = f2b(b2f(a[j]) + b2f(b[j]));
    *(ushort8v*)&sM[row * 136 + sg * 8] = o;
  }

  f32x4 acc[8];
#pragma unroll
  for (int nt = 0; nt < 8; ++nt) acc[nt] = (f32x4){0.f, 0.f, 0.f, 0.f};

  // ---- eattr @ W1c into acc; A direct from global (fp32->bf16 in-reg), B direct global
  const float* aep = eattr + (size_t)sEid[wv * 16 + ln15] * H;
#pragma unroll
  for (int c = 0; c < 2; ++c) {
    float4 q0 = *(const float4*)(aep + c * 64 + quad * 8);
    float4 q1 = *(const float4*)(aep + c * 64 + quad * 8 + 4);
    float4 q2 = *(const float4*)(aep + c * 64 + 32 + quad * 8);
    float4 q3 = *(const float4*)(aep + c * 64 + 32 + quad * 8 + 4);
    short8v af0, af1;
    af0[0] = (short)f2b(q0.x); af0[1] = (short)f2b(q0.y);
    af0[2] = (short)f2b(q0.z); af0[3] = (short)f2b(q0.w);
    af0[4] = (short)f2b(q1.x); af0[5] = (short)f2b(q1.y);
    af0[6] = (short)f2b(q1.z); af0[7] = (short)f2b(q1.w);
    af1[0] = (short)f2b(q2.x); af1[1] = (short)f2b(q2.y);
    af1[2] = (short)f2b(q2.z); af1[3] = (short)f2b(q2.w);
    af1[4] = (short)f2b(q3.x); af1[5] = (short)f2b(q3.y);
    af1[6] = (short)f2b(q3.z); af1[7] = (short)f2b(q3.w);
#pragma unroll
    for (int nt = 0; nt < 8; ++nt) {
      short8v bf = *(const short8v*)&mW1t[(size_t)(nt * 16 + ln15) * 384 + 256 + c * 64 + quad * 8];
      acc[nt] = __builtin_amdgcn_mfma_f32_16x16x32_bf16(af0, bf, acc[nt], 0, 0, 0);
    }
#pragma unroll
    for (int nt = 0; nt < 8; ++nt) {
      short8v bf = *(const short8v*)&mW1t[(size_t)(nt * 16 + ln15) * 384 + 256 + c * 64 + 32 + quad * 8];
      acc[nt] = __builtin_amdgcn_mfma_f32_16x16x32_bf16(af1, bf, acc[nt], 0, 0, 0);
    }
  }
  __syncthreads();                                              // B2: assembly visible

  // h1 = relu(acc + (XA+XB+mb1)) -> sM (read-modify-write of own C-layout elements)
#pragma unroll
  for (int nt = 0; nt < 8; ++nt) {
    int col = nt * 16 + ln15;
#pragma unroll
    for (int r = 0; r < 4; ++r) {
      int row = wv * 16 + quad * 4 + r;
      float xv = b2f(sM[row * 136 + col]);
      sM[row * 136 + col] = f2b(fmaxf(acc[nt][r] + xv, 0.f));
      acc[nt][r] = 0.f;
    }
  }
  __syncthreads();                                              // B3: h1 visible

  // ---- GEMM2: h1 [64][128] @ mW2 -> m, B direct global
#pragma unroll
  for (int c = 0; c < 2; ++c) {
    MFMA_STEP_G(sM, 136, c * 64, mW2t, 128, c * 64, acc)
  }
  __syncthreads();                                              // B4: GEMM2 A-reads done

  // m = acc + mb2 -> sM
#pragma unroll
  for (int nt = 0; nt < 8; ++nt) {
    int col = nt * 16 + ln15;
    float bb = mb2[col];
#pragma unroll
    for (int r = 0; r < 4; ++r) {
      int row = wv * 16 + quad * 4 + r;
      sM[row * 136 + col] = f2b(acc[nt][r] + bb);
    }
  }
  __syncthreads();                                              // B5: m visible

  // ---- acc MLP: w = relu(m @ aW1 + ab1) @ aW2 + ab2, B direct global
  float wp0 = 0.f, wp1 = 0.f, wp2 = 0.f, wp3 = 0.f;
#pragma unroll
  for (int h = 0; h < 2; ++h) {
#pragma unroll
    for (int nt = 0; nt < 8; ++nt) acc[nt] = (f32x4){0.f, 0.f, 0.f, 0.f};
#pragma unroll
    for (int c = 0; c < 2; ++c) {
      MFMA_STEP_G(sM, 136, c * 64, (aW1t + (size_t)h * 128 * 128), 128, c * 64, acc)
    }
#pragma unroll
    for (int nt = 0; nt < 8; ++nt) {
      int col = h * 128 + nt * 16 + ln15;
      float bb = ab1[col], a2 = aW2[col];
      wp0 += fmaxf(acc[nt][0] + bb, 0.f) * a2;
      wp1 += fmaxf(acc[nt][1] + bb, 0.f) * a2;
      wp2 += fmaxf(acc[nt][2] + bb, 0.f) * a2;
      wp3 += fmaxf(acc[nt][3] + bb, 0.f) * a2;
    }
  }
  // reduce across the 16 lanes of each quad (cols)
#pragma unroll
  for (int m = 1; m <= 8; m <<= 1) {
    wp0 += __shfl_xor(wp0, m, 64);
    wp1 += __shfl_xor(wp1, m, 64);
    wp2 += __shfl_xor(wp2, m, 64);
    wp3 += __shfl_xor(wp3, m, 64);
  }
  if (ln15 == 0) {
    float b2 = ab2[0];
    sW[wv * 16 + quad * 4 + 0] = wp0 + b2;
    sW[wv * 16 + quad * 4 + 1] = wp1 + b2;
    sW[wv * 16 + quad * 4 + 2] = wp2 + b2;
    sW[wv * 16 + quad * 4 + 3] = wp3 + b2;
  }
  __syncthreads();                                              // B6: sW visible

  // ---- per-edge acc_e into LDS ----
  if (tid < nv) {
    int s = sSrc[tid], d = sDst[tid];
    float rx = pos[s * 3 + 0] - pos[d * 3 + 0];
    float ry = pos[s * 3 + 1] - pos[d * 3 + 1];
    float rz = pos[s * 3 + 2] - pos[d * 3 + 2];
    float dist = sqrtf(rx * rx + ry * ry + rz * rz);
    float cf = sW[tid] / dist;
    sPE[tid * 3 + 0] = cf * rx;
    sPE[tid * 3 + 1] = cf * ry;
    sPE[tid * 3 + 2] = cf * rz;
  }
  __syncthreads();                                              // B7: sPE visible

  // ---- segment-reduced scatter: pdelta (dst-sorted tiles) ----
  if (tid < 3) {
    float run = 0.0f;
    int cur = -2;
    for (int e = 0; e < 64; ++e) {
      int d = (e < nv) ? sDst[e] : -1;
      if (d != cur) {
        if (cur >= 0 && run != 0.0f) atomicAdd(&pdelta[cur * 3 + tid], run);
        run = 0.0f;
        cur = d;
      }
      if (d >= 0) run += sPE[e * 3 + tid];
    }
    if (cur >= 0 && run != 0.0f) atomicAdd(&pdelta[cur * 3 + tid], run);
  }

  // ---- segment-reduced scatter: intra (m is bf16 in sM) ----
  if (do_intra) {
    int f = tid & 127;
    int hf = tid >> 7;
    int eBeg = hf * 32, eEnd = eBeg + 32;
    float run = 0.0f;
    int cur = -2;
    for (int e = eBeg; e < eEnd; ++e) {
      int d = (e < nv) ? sDst[e] : -1;
      if (d != cur) {
        if (cur >= 0 && run != 0.0f) atomicAdd(&intra[(size_t)cur * H + f], run);
        run = 0.0f;
        cur = d;
      }
      if (d >= 0) run += b2f(sM[e * 136 + f]);
    }
    if (cur >= 0 && run != 0.0f) atomicAdd(&intra[(size_t)cur * H + f], run);
  }
}

// ---------------- node kernel (bf16 MFMA, barrier-light) ----------------

__launch_bounds__(256, 4)
__global__ void k_node(const unsigned short* __restrict__ xb,
                       const float* __restrict__ intra,
                       const float* __restrict__ invd,
                       const unsigned short* __restrict__ nW1t, const float* __restrict__ nb1,
                       const unsigned short* __restrict__ nW2t, const float* __restrict__ nb2,
                       const float* __restrict__ pos_in,
                       const float* __restrict__ pdelta,
                       unsigned short* __restrict__ xb_out,
                       float* __restrict__ pos_out,
                       int compute_x)
{
  __shared__ unsigned short sH[64 * 136];
  const int tid = threadIdx.x;
  const int n0 = blockIdx.x * 64;

  if (tid < 192) {
    int n = n0 + tid / 3, cc = tid % 3;
    if (n < N_NODES)
      pos_out[n * 3 + cc] = pos_in[n * 3 + cc] + pdelta[n * 3 + cc] * invd[n];
  }
  if (!compute_x) return;

  const int wv = tid >> 6, lane = tid & 63, quad = lane >> 4, ln15 = lane & 15;
  const int arow = min(n0 + wv * 16 + ln15, N_NODES - 1);

  // A-fragments: xb part (reused across h) + intra*invd part (fp32 -> bf16 in-reg)
  short8v xfr[2][2];
#pragma unroll
  for (int c = 0; c < 2; ++c)
#pragma unroll
    for (int ks = 0; ks < 2; ++ks)
      xfr[c][ks] = *(const short8v*)&xb[(size_t)arow * H + c * 64 + ks * 32 + quad * 8];

  const float iv = invd[arow];
  short8v ifr[2][2];
#pragma unroll
  for (int c = 0; c < 2; ++c)
#pragma unroll
    for (int ks = 0; ks < 2; ++ks) {
      const float* ip = intra + (size_t)arow * H + c * 64 + ks * 32 + quad * 8;
      float4 p0 = *(const float4*)ip;
      float4 p1 = *(const float4*)(ip + 4);
      short8v v;
      v[0] = (short)f2b(p0.x * iv); v[1] = (short)f2b(p0.y * iv);
      v[2] = (short)f2b(p0.z * iv); v[3] = (short)f2b(p0.w * iv);
      v[4] = (short)f2b(p1.x * iv); v[5] = (short)f2b(p1.y * iv);
      v[6] = (short)f2b(p1.z * iv); v[7] = (short)f2b(p1.w * iv);
      ifr[c][ks] = v;
    }

  f32x4 xacc[8];
#pragma unroll
  for (int nt = 0; nt < 8; ++nt) xacc[nt] = (f32x4){0.f, 0.f, 0.f, 0.f};

#pragma unroll
  for (int h = 0; h < 2; ++h) {
    f32x4 acc[8];
#pragma unroll
    for (int nt = 0; nt < 8; ++nt) acc[nt] = (f32x4){0.f, 0.f, 0.f, 0.f};
    // GEMM-A: concat(xb, intra*invd) [64][256] @ nW1[:, h*128..], A in regs, B direct
#pragma unroll
    for (int c = 0; c < 4; ++c)
#pragma unroll
      for (int ks = 0; ks < 2; ++ks) {
        short8v af = (c < 2) ? xfr[c][ks] : ifr[c - 2][ks];
#pragma unroll
        for (int nt = 0; nt < 8; ++nt) {
          short8v bf = *(const short8v*)&nW1t[(size_t)(h * 128 + nt * 16 + ln15) * 256 + c * 64 + ks * 32 + quad * 8];
          acc[nt] = __builtin_amdgcn_mfma_f32_16x16x32_bf16(af, bf, acc[nt], 0, 0, 0);
        }
      }
    // h-half = relu(acc + nb1) -> sH (barrier protects h=1 overwrite vs h=0 reads)
    __syncthreads();
#pragma unroll
    for (int nt = 0; nt < 8; ++nt) {
      int col = nt * 16 + ln15;
      float bb = nb1[h * 128 + col];
#pragma unroll
      for (int r = 0; r < 4; ++r) {
        int row = wv * 16 + quad * 4 + r;
        sH[row * 136 + col] = f2b(fmaxf(acc[nt][r] + bb, 0.f));
      }
    }
    __syncthreads();
    // GEMM-B partial: sH [64][128] @ nW2[h*128.., :] into xacc, B direct
#pragma unroll
    for (int c2 = 0; c2 < 2; ++c2) {
      MFMA_STEP_G(sH, 136, c2 * 64, nW2t, 256, h * 128 + c2 * 64, xacc)
    }
  }
  // x_out = xacc + nb2 (bf16)
#pragma unroll
  for (int nt = 0; nt < 8; ++nt) {
    int col = nt * 16 + ln15;
    float bb = nb2[col];
#pragma unroll
    for (int r = 0; r < 4; ++r) {
      int row = n0 + wv * 16 + quad * 4 + r;
      if (row < N_NODES)
        xb_out[(size_t)row * H + col] = f2b(xacc[nt][r] + bb);
    }
  }
}

extern "C" void kernel_launch(void* const* d_in, const int* in_sizes, int n_in,
                              void* d_out, int out_size, void* d_ws, size_t ws_size,
                              hipStream_t stream) {
  const float* x0    = (const float*)d_in[0];
  const int*   eidx  = (const int*)d_in[1];
  const float* eattr = (const float*)d_in[2];
  const float* pos0  = (const float*)d_in[3];
  const float* mW1 = (const float*)d_in[4];
  const float* mb1 = (const float*)d_in[5];
  const float* mW2 = (const float*)d_in[6];
  const float* mb2 = (const float*)d_in[7];
  const float* aW1 = (const float*)d_in[8];
  const float* ab1 = (const float*)d_in[9];
  const float* aW2 = (const float*)d_in[10];
  const float* ab2 = (const float*)d_in[11];
  const float* nW1 = (const float*)d_in[12];
  const float* nb1 = (const float*)d_in[13];
  const float* nW2 = (const float*)d_in[14];
  const float* nb2 = (const float*)d_in[15];
  const int* srcI = eidx;
  const int* dstI = eidx + N_EDGES;

  char* wsb = (char*)d_ws;
  int*   degC    = (int*)wsb;                     wsb += (size_t)N_NODES * 4;
  int*   cursor  = (int*)wsb;                     wsb += (size_t)N_NODES * 4;
  int*   chunkS  = (int*)wsb;                     wsb += 256 * 4;
  int*   sorted  = (int*)wsb;                     wsb += (size_t)N_EDGES * 4;
  float* invd    = (float*)wsb;                   wsb += (size_t)N_NODES * 4;
  float* pdelta  = (float*)wsb;                   wsb += (size_t)3 * N_NODES * 4;
  float* pos_a   = (float*)wsb;                   wsb += (size_t)3 * N_NODES * 4;
  float* pos_b   = (float*)wsb;                   wsb += (size_t)3 * N_NODES * 4;
  float* intra   = (float*)wsb;                   wsb += (size_t)N_NODES * H * 4;
  unsigned short* xb0  = (unsigned short*)wsb;    wsb += (size_t)N_NODES * H * 2;
  unsigned short* xb_a = (unsigned short*)wsb;    wsb += (size_t)N_NODES * H * 2;
  unsigned short* xb_b = (unsigned short*)wsb;    wsb += (size_t)N_NODES * H * 2;
  unsigned short* xabW = (unsigned short*)wsb;    wsb += (size_t)N_NODES * 256 * 2;
  unsigned short* mW1t = (unsigned short*)wsb;    wsb += (size_t)NL * 128 * 384 * 2;
  unsigned short* mW2t = (unsigned short*)wsb;    wsb += (size_t)NL * 128 * 128 * 2;
  unsigned short* aW1t = (unsigned short*)wsb;    wsb += (size_t)NL * 256 * 128 * 2;
  unsigned short* nW1t = (unsigned short*)wsb;    wsb += (size_t)NL * 256 * 256 * 2;
  unsigned short* nW2t = (unsigned short*)wsb;    wsb += (size_t)NL * 128 * 256 * 2;

  // counting sort of edges by dst (every launch; ws is re-poisoned)
  hipMemsetAsync(degC, 0, N_NODES * sizeof(int), stream);
  k_deg_i<<<(N_EDGES + 255) / 256, 256, 0, stream>>>(dstI, degC);
  k_inv<<<(N_NODES + 255) / 256, 256, 0, stream>>>(degC, invd);
  k_scan1<<<NCHUNK, SCAN_B, 0, stream>>>(degC, cursor, chunkS);
  k_scan2<<<1, SCAN_B, 0, stream>>>(chunkS);
  k_scan3<<<NCHUNK, SCAN_B, 0, stream>>>(cursor, chunkS);
  k_scatter_sort<<<(N_EDGES + 255) / 256, 256, 0, stream>>>(dstI, cursor, sorted);

  // bf16 conversions
  {
    int n4 = N_NODES * H / 4;
    k_cvt_x<<<(n4 + 255) / 256, 256, 0, stream>>>(x0, xb0, n4);
    int t1 = NL * 384 * 128;
    k_cvt_wt<<<(t1 + 255) / 256, 256, 0, stream>>>(mW1, mW1t, 384, 128, t1);
    int t2 = NL * 128 * 128;
    k_cvt_wt<<<(t2 + 255) / 256, 256, 0, stream>>>(mW2, mW2t, 128, 128, t2);
    int t3 = NL * 128 * 256;
    k_cvt_wt<<<(t3 + 255) / 256, 256, 0, stream>>>(aW1, aW1t, 128, 256, t3);
    int t4 = NL * 256 * 256;
    k_cvt_wt<<<(t4 + 255) / 256, 256, 0, stream>>>(nW1, nW1t, 256, 256, t4);
    int t5 = NL * 256 * 128;
    k_cvt_wt<<<(t5 + 255) / 256, 256, 0, stream>>>(nW2, nW2t, 256, 128, t5);
  }

  const unsigned short* xc = xb0;
  const float* pc = pos0;
  float* pos_out_final = (float*)d_out;

  for (int l = 0; l < NL; ++l) {
    int last = (l == NL - 1);
    hipMemsetAsync(pdelta, 0, 3 * N_NODES * sizeof(float), stream);
    if (!last)
      hipMemsetAsync(intra, 0, (size_t)N_NODES * H * sizeof(float), stream);

    // node-side precompute of the x-dependent halves of the message MLP input
    k_xab<<<(N_NODES + 63) / 64, 256, 0, stream>>>(
        xc, mW1t + (size_t)l * 128 * 384, mb1 + (size_t)l * 128, xabW);

    k_edge<<<(N_EDGES + 63) / 64, 256, 0, stream>>>(
        xabW, pc, eattr, srcI, dstI, sorted,
        mW1t + (size_t)l * 128 * 384,
        mW2t + (size_t)l * 128 * 128, mb2 + (size_t)l * 128,
        aW1t + (size_t)l * 256 * 128, ab1 + (size_t)l * 256,
        aW2 + (size_t)l * 256, ab2 + l,
        intra, pdelta, last ? 0 : 1);

    float* pn = last ? pos_out_final : (l == 0 ? pos_a : pos_b);
    unsigned short* xn = (l == 0) ? xb_a : xb_b;
    k_node<<<(N_NODES + 63) / 64, 256, 0, stream>>>(
        xc, intra, invd,
        nW1t + (size_t)l * 256 * 256, nb1 + (size_t)l * 256,
        nW2t + (size_t)l * 128 * 256, nb2 + (size_t)l * 128,
        pc, pdelta, xn, pn, last ? 0 : 1);

    xc = xn;
    pc = pn;
  }
}

// Round 3
// 2271.681 us; speedup vs baseline: 1.1194x; 1.1194x over previous
//
#include <hip/hip_runtime.h>
#include <hip/hip_bf16.h>
#include <math.h>

#define N_NODES 50000
#define N_EDGES 500000
#define H 128
#define NL 3
#define SCAN_B 256
#define NCHUNK ((N_NODES + SCAN_B - 1) / SCAN_B)

typedef short short8v __attribute__((ext_vector_type(8)));
typedef float f32x4 __attribute__((ext_vector_type(4)));
typedef unsigned short ushort8v __attribute__((ext_vector_type(8)));
typedef unsigned short ushort4v __attribute__((ext_vector_type(4)));

__device__ __forceinline__ unsigned short f2b(float f) {
  __hip_bfloat16 h = __float2bfloat16(f);
  return __builtin_bit_cast(unsigned short, h);
}
__device__ __forceinline__ float b2f(unsigned short s) {
  unsigned u = (unsigned)s << 16;
  return __builtin_bit_cast(float, u);
}

// ---------------- counting sort of edges by dst ----------------

__global__ void k_deg_i(const int* __restrict__ dst, int* __restrict__ degC) {
  int e = blockIdx.x * blockDim.x + threadIdx.x;
  if (e < N_EDGES) atomicAdd(&degC[dst[e]], 1);
}

__global__ void k_inv(const int* __restrict__ degC, float* __restrict__ invd) {
  int i = blockIdx.x * blockDim.x + threadIdx.x;
  if (i < N_NODES) invd[i] = 1.0f / fmaxf((float)degC[i], 1.0f);
}

__global__ void k_scan1(const int* __restrict__ degC, int* __restrict__ cursor,
                        int* __restrict__ chunkSum) {
  __shared__ int s[SCAN_B];
  int t = threadIdx.x, i = blockIdx.x * SCAN_B + t;
  int v = (i < N_NODES) ? degC[i] : 0;
  s[t] = v;
  __syncthreads();
  for (int o = 1; o < SCAN_B; o <<= 1) {
    int u = (t >= o) ? s[t - o] : 0;
    __syncthreads();
    s[t] += u;
    __syncthreads();
  }
  if (i < N_NODES) cursor[i] = s[t] - v;
  if (t == SCAN_B - 1) chunkSum[blockIdx.x] = s[t];
}

__global__ void k_scan2(int* __restrict__ chunkSum) {
  __shared__ int s[SCAN_B];
  int t = threadIdx.x;
  int v = (t < NCHUNK) ? chunkSum[t] : 0;
  s[t] = v;
  __syncthreads();
  for (int o = 1; o < SCAN_B; o <<= 1) {
    int u = (t >= o) ? s[t - o] : 0;
    __syncthreads();
    s[t] += u;
    __syncthreads();
  }
  if (t < NCHUNK) chunkSum[t] = s[t] - v;
}

__global__ void k_scan3(int* __restrict__ cursor, const int* __restrict__ chunkSum) {
  int i = blockIdx.x * SCAN_B + threadIdx.x;
  if (i < N_NODES) cursor[i] += chunkSum[blockIdx.x];
}

__global__ void k_scatter_sort(const int* __restrict__ dst, int* __restrict__ cursor,
                               int* __restrict__ sorted) {
  int e = blockIdx.x * blockDim.x + threadIdx.x;
  if (e < N_EDGES) {
    int p = atomicAdd(&cursor[dst[e]], 1);
    sorted[p] = e;
  }
}

// ---------------- fp32 -> bf16 conversions ----------------

__global__ void k_cvt_x(const float* __restrict__ x, unsigned short* __restrict__ xb, int n4) {
  int i = blockIdx.x * blockDim.x + threadIdx.x;
  if (i < n4) {
    float4 v = ((const float4*)x)[i];
    ushort4v o;
    o[0] = f2b(v.x); o[1] = f2b(v.y); o[2] = f2b(v.z); o[3] = f2b(v.w);
    ((ushort4v*)xb)[i] = o;
  }
}

// src [L][K][N] fp32 -> dst [L][N][K] bf16
__global__ void k_cvt_wt(const float* __restrict__ src, unsigned short* __restrict__ dst,
                         int K, int N, int total) {
  int i = blockIdx.x * blockDim.x + threadIdx.x;
  if (i < total) {
    int l = i / (K * N);
    int rem = i - l * K * N;
    int k = rem / N;
    int n = rem - k * N;
    dst[((size_t)l * N + n) * K + k] = f2b(src[i]);
  }
}

// ---------------- MFMA helper: A from LDS, B direct from global [N][K] bf16 ----------------
// wave wv owns output rows wv*16..+15; 8 N-tiles of 16 cols.
// A fragment: row = wv*16 + (lane&15), k = AKOFF + ks*32 + quad*8 (8 contiguous bf16)
// B fragment: row n = nt*16 + (lane&15) of BP (pitch BPITCH), same k window (identical
//   addresses across the 4 waves -> L1 broadcast; weights are L2-resident)
// C/D: D[wv*16 + quad*4 + r][nt*16 + (lane&15)] = acc[nt][r]
#define MFMA_STEP_G(AP, APITCH, AKOFF, BP, BPITCH, BKOFF, ACCN)                    \
  { _Pragma("unroll")                                                              \
    for (int ks_ = 0; ks_ < 2; ++ks_) {                                            \
      short8v af_ = *(const short8v*)&AP[(wv * 16 + ln15) * (APITCH) + (AKOFF) + ks_ * 32 + quad * 8]; \
      _Pragma("unroll")                                                            \
      for (int nt_ = 0; nt_ < 8; ++nt_) {                                          \
        short8v bf_ = *(const short8v*)&BP[(size_t)(nt_ * 16 + ln15) * (BPITCH) + (BKOFF) + ks_ * 32 + quad * 8]; \
        ACCN[nt_] = __builtin_amdgcn_mfma_f32_16x16x32_bf16(af_, bf_, ACCN[nt_], 0, 0, 0); \
      } } }

// ---------------- per-layer node-side precompute: XAB = x @ [W1a|W1b] (+mb1 folded) ----
// out: xab [N_NODES][256] bf16, cols 0..127 = x@W1a + mb1 (dst part), 128..255 = x@W1b

__launch_bounds__(256, 4)
__global__ void k_xab(const unsigned short* __restrict__ xb,
                      const unsigned short* __restrict__ mW1t,  // [128n][384k]
                      const float* __restrict__ mb1,
                      unsigned short* __restrict__ xab)
{
  const int tid = threadIdx.x;
  const int n0 = blockIdx.x * 64;
  const int wv = tid >> 6, lane = tid & 63, quad = lane >> 4, ln15 = lane & 15;
  const int arow = min(n0 + wv * 16 + ln15, N_NODES - 1);

  // A fragments (K=128 of this node row), reused across both output halves
  short8v afr[2][2];
#pragma unroll
  for (int c = 0; c < 2; ++c)
#pragma unroll
    for (int ks = 0; ks < 2; ++ks)
      afr[c][ks] = *(const short8v*)&xb[(size_t)arow * H + c * 64 + ks * 32 + quad * 8];

#pragma unroll
  for (int h = 0; h < 2; ++h) {
    f32x4 acc[8];
#pragma unroll
    for (int nt = 0; nt < 8; ++nt) acc[nt] = (f32x4){0.f, 0.f, 0.f, 0.f};
#pragma unroll
    for (int c = 0; c < 2; ++c)
#pragma unroll
      for (int ks = 0; ks < 2; ++ks)
#pragma unroll
        for (int nt = 0; nt < 8; ++nt) {
          short8v bf = *(const short8v*)&mW1t[(size_t)(nt * 16 + ln15) * 384 + h * 128 + c * 64 + ks * 32 + quad * 8];
          acc[nt] = __builtin_amdgcn_mfma_f32_16x16x32_bf16(afr[c][ks], bf, acc[nt], 0, 0, 0);
        }
#pragma unroll
    for (int nt = 0; nt < 8; ++nt) {
      int col = nt * 16 + ln15;
      float bb = (h == 0) ? mb1[col] : 0.f;
#pragma unroll
      for (int r = 0; r < 4; ++r) {
        int row = n0 + wv * 16 + quad * 4 + r;
        if (row < N_NODES)
          xab[(size_t)row * 256 + h * 128 + col] = f2b(acc[nt][r] + bb);
      }
    }
  }
}

// ---------------- fused edge kernel (bf16 MFMA, barrier-light) ----------------

__launch_bounds__(256, 4)
__global__ void k_edge(const unsigned short* __restrict__ xab,   // [N][256] bf16
                       const float* __restrict__ pos,
                       const float* __restrict__ eattr,
                       const int* __restrict__ srcI,
                       const int* __restrict__ dstI,
                       const int* __restrict__ sorted,
                       const unsigned short* __restrict__ mW1t,
                       const unsigned short* __restrict__ mW2t, const float* __restrict__ mb2,
                       const unsigned short* __restrict__ aW1t, const float* __restrict__ ab1,
                       const float* __restrict__ aW2, const float* __restrict__ ab2,
                       float* __restrict__ intra,
                       float* __restrict__ pdelta,
                       int do_intra)
{
  __shared__ unsigned short sM[64 * 136];   // XA+XB -> h1 -> m; [64][128] bf16, pitch 136
  __shared__ int sEid[64], sSrc[64], sDst[64];
  __shared__ float sW[64];
  __shared__ float sPE[64 * 3];

  const int tid = threadIdx.x;
  // bijective XCD-aware swizzle: consecutive dst-sorted tiles land on the same XCD
  const int nwg = gridDim.x;
  const int q_ = nwg >> 3, r_ = nwg & 7;
  const int xcd = blockIdx.x & 7, bidx = blockIdx.x >> 3;
  const int bid = (xcd < r_ ? xcd * (q_ + 1) : r_ * (q_ + 1) + (xcd - r_) * q_) + bidx;
  const int e0 = bid * 64;
  const int nv = min(N_EDGES - e0, 64);
  if (tid < 64) {
    int idx = min(e0 + tid, N_EDGES - 1);
    int eid = sorted[idx];
    sEid[tid] = eid; sSrc[tid] = srcI[eid]; sDst[tid] = dstI[eid];
  }
  __syncthreads();                                              // B1

  const int wv = tid >> 6, lane = tid & 63, quad = lane >> 4, ln15 = lane & 15;

  // ---- assemble XA[dst] + XB[src] (bias pre-folded) into sM ----
#pragma unroll
  for (int i_ = 0; i_ < 4; ++i_) {
    int flat = tid + i_ * 256;          // 0..1023 = 64 rows x 16 seg8
    int row = flat >> 4, sg = flat & 15;
    ushort8v a = *(const ushort8v*)&xab[(size_t)sDst[row] * 256 + sg * 8];
    ushort8v b = *(const ushort8v*)&xab[(size_t)sSrc[row] * 256 + 128 + sg * 8];
    ushort8v o;
#pragma unroll
    for (int j = 0; j < 8; ++j) o[j] = f2b(b2f(a[j]) + b2f(b[j]));
    *(ushort8v*)&sM[row * 136 + sg * 8] = o;
  }

  f32x4 acc[8];
#pragma unroll
  for (int nt = 0; nt < 8; ++nt) acc[nt] = (f32x4){0.f, 0.f, 0.f, 0.f};

  // ---- eattr @ W1c into acc; A direct from global (fp32->bf16 in-reg), B direct global
  // one 16B-convert + 8-MFMA group at a time to keep live range small
  const float* aep = eattr + (size_t)sEid[wv * 16 + ln15] * H;
#pragma unroll
  for (int c = 0; c < 2; ++c) {
#pragma unroll
    for (int hf = 0; hf < 2; ++hf) {
      float4 q0 = *(const float4*)(aep + c * 64 + hf * 32 + quad * 8);
      float4 q1 = *(const float4*)(aep + c * 64 + hf * 32 + quad * 8 + 4);
      short8v af;
      af[0] = (short)f2b(q0.x); af[1] = (short)f2b(q0.y);
      af[2] = (short)f2b(q0.z); af[3] = (short)f2b(q0.w);
      af[4] = (short)f2b(q1.x); af[5] = (short)f2b(q1.y);
      af[6] = (short)f2b(q1.z); af[7] = (short)f2b(q1.w);
#pragma unroll
      for (int nt = 0; nt < 8; ++nt) {
        short8v bf = *(const short8v*)&mW1t[(size_t)(nt * 16 + ln15) * 384 + 256 + c * 64 + hf * 32 + quad * 8];
        acc[nt] = __builtin_amdgcn_mfma_f32_16x16x32_bf16(af, bf, acc[nt], 0, 0, 0);
      }
    }
  }
  __syncthreads();                                              // B2: assembly visible

  // h1 = relu(acc + (XA+XB+mb1)) -> sM (read-modify-write of own C-layout elements)
#pragma unroll
  for (int nt = 0; nt < 8; ++nt) {
    int col = nt * 16 + ln15;
#pragma unroll
    for (int r = 0; r < 4; ++r) {
      int row = wv * 16 + quad * 4 + r;
      float xv = b2f(sM[row * 136 + col]);
      sM[row * 136 + col] = f2b(fmaxf(acc[nt][r] + xv, 0.f));
      acc[nt][r] = 0.f;
    }
  }
  __syncthreads();                                              // B3: h1 visible

  // ---- GEMM2: h1 [64][128] @ mW2 -> m, B direct global
#pragma unroll
  for (int c = 0; c < 2; ++c) {
    MFMA_STEP_G(sM, 136, c * 64, mW2t, 128, c * 64, acc)
  }
  __syncthreads();                                              // B4: GEMM2 A-reads done

  // m = acc + mb2 -> sM
#pragma unroll
  for (int nt = 0; nt < 8; ++nt) {
    int col = nt * 16 + ln15;
    float bb = mb2[col];
#pragma unroll
    for (int r = 0; r < 4; ++r) {
      int row = wv * 16 + quad * 4 + r;
      sM[row * 136 + col] = f2b(acc[nt][r] + bb);
    }
  }
  __syncthreads();                                              // B5: m visible

  // ---- acc MLP: w = relu(m @ aW1 + ab1) @ aW2 + ab2, B direct global
  float wp0 = 0.f, wp1 = 0.f, wp2 = 0.f, wp3 = 0.f;
#pragma unroll
  for (int h = 0; h < 2; ++h) {
#pragma unroll
    for (int nt = 0; nt < 8; ++nt) acc[nt] = (f32x4){0.f, 0.f, 0.f, 0.f};
#pragma unroll
    for (int c = 0; c < 2; ++c) {
      MFMA_STEP_G(sM, 136, c * 64, (aW1t + (size_t)h * 128 * 128), 128, c * 64, acc)
    }
#pragma unroll
    for (int nt = 0; nt < 8; ++nt) {
      int col = h * 128 + nt * 16 + ln15;
      float bb = ab1[col], a2 = aW2[col];
      wp0 += fmaxf(acc[nt][0] + bb, 0.f) * a2;
      wp1 += fmaxf(acc[nt][1] + bb, 0.f) * a2;
      wp2 += fmaxf(acc[nt][2] + bb, 0.f) * a2;
      wp3 += fmaxf(acc[nt][3] + bb, 0.f) * a2;
    }
  }
  // reduce across the 16 lanes of each quad (cols)
#pragma unroll
  for (int m = 1; m <= 8; m <<= 1) {
    wp0 += __shfl_xor(wp0, m, 64);
    wp1 += __shfl_xor(wp1, m, 64);
    wp2 += __shfl_xor(wp2, m, 64);
    wp3 += __shfl_xor(wp3, m, 64);
  }
  if (ln15 == 0) {
    float b2 = ab2[0];
    sW[wv * 16 + quad * 4 + 0] = wp0 + b2;
    sW[wv * 16 + quad * 4 + 1] = wp1 + b2;
    sW[wv * 16 + quad * 4 + 2] = wp2 + b2;
    sW[wv * 16 + quad * 4 + 3] = wp3 + b2;
  }
  __syncthreads();                                              // B6: sW visible

  // ---- per-edge acc_e into LDS ----
  if (tid < nv) {
    int s = sSrc[tid], d = sDst[tid];
    float rx = pos[s * 3 + 0] - pos[d * 3 + 0];
    float ry = pos[s * 3 + 1] - pos[d * 3 + 1];
    float rz = pos[s * 3 + 2] - pos[d * 3 + 2];
    float dist = sqrtf(rx * rx + ry * ry + rz * rz);
    float cf = sW[tid] / dist;
    sPE[tid * 3 + 0] = cf * rx;
    sPE[tid * 3 + 1] = cf * ry;
    sPE[tid * 3 + 2] = cf * rz;
  }
  __syncthreads();                                              // B7: sPE visible

  // ---- segment-reduced scatter: pdelta (dst-sorted tiles) ----
  if (tid < 3) {
    float run = 0.0f;
    int cur = -2;
    for (int e = 0; e < 64; ++e) {
      int d = (e < nv) ? sDst[e] : -1;
      if (d != cur) {
        if (cur >= 0 && run != 0.0f) atomicAdd(&pdelta[cur * 3 + tid], run);
        run = 0.0f;
        cur = d;
      }
      if (d >= 0) run += sPE[e * 3 + tid];
    }
    if (cur >= 0 && run != 0.0f) atomicAdd(&pdelta[cur * 3 + tid], run);
  }

  // ---- segment-reduced scatter: intra (m is bf16 in sM) ----
  if (do_intra) {
    int f = tid & 127;
    int hf = tid >> 7;
    int eBeg = hf * 32, eEnd = eBeg + 32;
    float run = 0.0f;
    int cur = -2;
    for (int e = eBeg; e < eEnd; ++e) {
      int d = (e < nv) ? sDst[e] : -1;
      if (d != cur) {
        if (cur >= 0 && run != 0.0f) atomicAdd(&intra[(size_t)cur * H + f], run);
        run = 0.0f;
        cur = d;
      }
      if (d >= 0) run += b2f(sM[e * 136 + f]);
    }
    if (cur >= 0 && run != 0.0f) atomicAdd(&intra[(size_t)cur * H + f], run);
  }
}

// ---------------- node kernel (bf16 MFMA, barrier-light) ----------------

__launch_bounds__(256, 3)
__global__ void k_node(const unsigned short* __restrict__ xb,
                       const float* __restrict__ intra,
                       const float* __restrict__ invd,
                       const unsigned short* __restrict__ nW1t, const float* __restrict__ nb1,
                       const unsigned short* __restrict__ nW2t, const float* __restrict__ nb2,
                       const float* __restrict__ pos_in,
                       const float* __restrict__ pdelta,
                       unsigned short* __restrict__ xb_out,
                       float* __restrict__ pos_out,
                       int compute_x)
{
  __shared__ unsigned short sH[64 * 136];
  const int tid = threadIdx.x;
  const int n0 = blockIdx.x * 64;

  if (tid < 192) {
    int n = n0 + tid / 3, cc = tid % 3;
    if (n < N_NODES)
      pos_out[n * 3 + cc] = pos_in[n * 3 + cc] + pdelta[n * 3 + cc] * invd[n];
  }
  if (!compute_x) return;

  const int wv = tid >> 6, lane = tid & 63, quad = lane >> 4, ln15 = lane & 15;
  const int arow = min(n0 + wv * 16 + ln15, N_NODES - 1);

  // A-fragments: xb part (reused across h) + intra*invd part (fp32 -> bf16 in-reg)
  short8v xfr[2][2];
#pragma unroll
  for (int c = 0; c < 2; ++c)
#pragma unroll
    for (int ks = 0; ks < 2; ++ks)
      xfr[c][ks] = *(const short8v*)&xb[(size_t)arow * H + c * 64 + ks * 32 + quad * 8];

  const float iv = invd[arow];
  short8v ifr[2][2];
#pragma unroll
  for (int c = 0; c < 2; ++c)
#pragma unroll
    for (int ks = 0; ks < 2; ++ks) {
      const float* ip = intra + (size_t)arow * H + c * 64 + ks * 32 + quad * 8;
      float4 p0 = *(const float4*)ip;
      float4 p1 = *(const float4*)(ip + 4);
      short8v v;
      v[0] = (short)f2b(p0.x * iv); v[1] = (short)f2b(p0.y * iv);
      v[2] = (short)f2b(p0.z * iv); v[3] = (short)f2b(p0.w * iv);
      v[4] = (short)f2b(p1.x * iv); v[5] = (short)f2b(p1.y * iv);
      v[6] = (short)f2b(p1.z * iv); v[7] = (short)f2b(p1.w * iv);
      ifr[c][ks] = v;
    }

  f32x4 xacc[8];
#pragma unroll
  for (int nt = 0; nt < 8; ++nt) xacc[nt] = (f32x4){0.f, 0.f, 0.f, 0.f};

#pragma unroll
  for (int h = 0; h < 2; ++h) {
    f32x4 acc[8];
#pragma unroll
    for (int nt = 0; nt < 8; ++nt) acc[nt] = (f32x4){0.f, 0.f, 0.f, 0.f};
    // GEMM-A: concat(xb, intra*invd) [64][256] @ nW1[:, h*128..], A in regs, B direct
#pragma unroll
    for (int c = 0; c < 4; ++c)
#pragma unroll
      for (int ks = 0; ks < 2; ++ks) {
        short8v af = (c < 2) ? xfr[c][ks] : ifr[c - 2][ks];
#pragma unroll
        for (int nt = 0; nt < 8; ++nt) {
          short8v bf = *(const short8v*)&nW1t[(size_t)(h * 128 + nt * 16 + ln15) * 256 + c * 64 + ks * 32 + quad * 8];
          acc[nt] = __builtin_amdgcn_mfma_f32_16x16x32_bf16(af, bf, acc[nt], 0, 0, 0);
        }
      }
    // h-half = relu(acc + nb1) -> sH (barrier protects h=1 overwrite vs h=0 reads)
    __syncthreads();
#pragma unroll
    for (int nt = 0; nt < 8; ++nt) {
      int col = nt * 16 + ln15;
      float bb = nb1[h * 128 + col];
#pragma unroll
      for (int r = 0; r < 4; ++r) {
        int row = wv * 16 + quad * 4 + r;
        sH[row * 136 + col] = f2b(fmaxf(acc[nt][r] + bb, 0.f));
      }
    }
    __syncthreads();
    // GEMM-B partial: sH [64][128] @ nW2[h*128.., :] into xacc, B direct
#pragma unroll
    for (int c2 = 0; c2 < 2; ++c2) {
      MFMA_STEP_G(sH, 136, c2 * 64, nW2t, 256, h * 128 + c2 * 64, xacc)
    }
  }
  // x_out = xacc + nb2 (bf16)
#pragma unroll
  for (int nt = 0; nt < 8; ++nt) {
    int col = nt * 16 + ln15;
    float bb = nb2[col];
#pragma unroll
    for (int r = 0; r < 4; ++r) {
      int row = n0 + wv * 16 + quad * 4 + r;
      if (row < N_NODES)
        xb_out[(size_t)row * H + col] = f2b(xacc[nt][r] + bb);
    }
  }
}

extern "C" void kernel_launch(void* const* d_in, const int* in_sizes, int n_in,
                              void* d_out, int out_size, void* d_ws, size_t ws_size,
                              hipStream_t stream) {
  const float* x0    = (const float*)d_in[0];
  const int*   eidx  = (const int*)d_in[1];
  const float* eattr = (const float*)d_in[2];
  const float* pos0  = (const float*)d_in[3];
  const float* mW1 = (const float*)d_in[4];
  const float* mb1 = (const float*)d_in[5];
  const float* mW2 = (const float*)d_in[6];
  const float* mb2 = (const float*)d_in[7];
  const float* aW1 = (const float*)d_in[8];
  const float* ab1 = (const float*)d_in[9];
  const float* aW2 = (const float*)d_in[10];
  const float* ab2 = (const float*)d_in[11];
  const float* nW1 = (const float*)d_in[12];
  const float* nb1 = (const float*)d_in[13];
  const float* nW2 = (const float*)d_in[14];
  const float* nb2 = (const float*)d_in[15];
  const int* srcI = eidx;
  const int* dstI = eidx + N_EDGES;

  char* wsb = (char*)d_ws;
  int*   degC    = (int*)wsb;                     wsb += (size_t)N_NODES * 4;
  int*   cursor  = (int*)wsb;                     wsb += (size_t)N_NODES * 4;
  int*   chunkS  = (int*)wsb;                     wsb += 256 * 4;
  int*   sorted  = (int*)wsb;                     wsb += (size_t)N_EDGES * 4;
  float* invd    = (float*)wsb;                   wsb += (size_t)N_NODES * 4;
  float* pdelta  = (float*)wsb;                   wsb += (size_t)3 * N_NODES * 4;
  float* pos_a   = (float*)wsb;                   wsb += (size_t)3 * N_NODES * 4;
  float* pos_b   = (float*)wsb;                   wsb += (size_t)3 * N_NODES * 4;
  float* intra   = (float*)wsb;                   wsb += (size_t)N_NODES * H * 4;
  unsigned short* xb0  = (unsigned short*)wsb;    wsb += (size_t)N_NODES * H * 2;
  unsigned short* xb_a = (unsigned short*)wsb;    wsb += (size_t)N_NODES * H * 2;
  unsigned short* xb_b = (unsigned short*)wsb;    wsb += (size_t)N_NODES * H * 2;
  unsigned short* xabW = (unsigned short*)wsb;    wsb += (size_t)N_NODES * 256 * 2;
  unsigned short* mW1t = (unsigned short*)wsb;    wsb += (size_t)NL * 128 * 384 * 2;
  unsigned short* mW2t = (unsigned short*)wsb;    wsb += (size_t)NL * 128 * 128 * 2;
  unsigned short* aW1t = (unsigned short*)wsb;    wsb += (size_t)NL * 256 * 128 * 2;
  unsigned short* nW1t = (unsigned short*)wsb;    wsb += (size_t)NL * 256 * 256 * 2;
  unsigned short* nW2t = (unsigned short*)wsb;    wsb += (size_t)NL * 128 * 256 * 2;

  // counting sort of edges by dst (every launch; ws is re-poisoned)
  hipMemsetAsync(degC, 0, N_NODES * sizeof(int), stream);
  k_deg_i<<<(N_EDGES + 255) / 256, 256, 0, stream>>>(dstI, degC);
  k_inv<<<(N_NODES + 255) / 256, 256, 0, stream>>>(degC, invd);
  k_scan1<<<NCHUNK, SCAN_B, 0, stream>>>(degC, cursor, chunkS);
  k_scan2<<<1, SCAN_B, 0, stream>>>(chunkS);
  k_scan3<<<NCHUNK, SCAN_B, 0, stream>>>(cursor, chunkS);
  k_scatter_sort<<<(N_EDGES + 255) / 256, 256, 0, stream>>>(dstI, cursor, sorted);

  // bf16 conversions
  {
    int n4 = N_NODES * H / 4;
    k_cvt_x<<<(n4 + 255) / 256, 256, 0, stream>>>(x0, xb0, n4);
    int t1 = NL * 384 * 128;
    k_cvt_wt<<<(t1 + 255) / 256, 256, 0, stream>>>(mW1, mW1t, 384, 128, t1);
    int t2 = NL * 128 * 128;
    k_cvt_wt<<<(t2 + 255) / 256, 256, 0, stream>>>(mW2, mW2t, 128, 128, t2);
    int t3 = NL * 128 * 256;
    k_cvt_wt<<<(t3 + 255) / 256, 256, 0, stream>>>(aW1, aW1t, 128, 256, t3);
    int t4 = NL * 256 * 256;
    k_cvt_wt<<<(t4 + 255) / 256, 256, 0, stream>>>(nW1, nW1t, 256, 256, t4);
    int t5 = NL * 256 * 128;
    k_cvt_wt<<<(t5 + 255) / 256, 256, 0, stream>>>(nW2, nW2t, 256, 128, t5);
  }

  const unsigned short* xc = xb0;
  const float* pc = pos0;
  float* pos_out_final = (float*)d_out;

  for (int l = 0; l < NL; ++l) {
    int last = (l == NL - 1);
    hipMemsetAsync(pdelta, 0, 3 * N_NODES * sizeof(float), stream);
    if (!last)
      hipMemsetAsync(intra, 0, (size_t)N_NODES * H * sizeof(float), stream);

    // node-side precompute of the x-dependent halves of the message MLP input
    k_xab<<<(N_NODES + 63) / 64, 256, 0, stream>>>(
        xc, mW1t + (size_t)l * 128 * 384, mb1 + (size_t)l * 128, xabW);

    k_edge<<<(N_EDGES + 63) / 64, 256, 0, stream>>>(
        xabW, pc, eattr, srcI, dstI, sorted,
        mW1t + (size_t)l * 128 * 384,
        mW2t + (size_t)l * 128 * 128, mb2 + (size_t)l * 128,
        aW1t + (size_t)l * 256 * 128, ab1 + (size_t)l * 256,
        aW2 + (size_t)l * 256, ab2 + l,
        intra, pdelta, last ? 0 : 1);

    float* pn = last ? pos_out_final : (l == 0 ? pos_a : pos_b);
    unsigned short* xn = (l == 0) ? xb_a : xb_b;
    k_node<<<(N_NODES + 63) / 64, 256, 0, stream>>>(
        xc, intra, invd,
        nW1t + (size_t)l * 256 * 256, nb1 + (size_t)l * 256,
        nW2t + (size_t)l * 128 * 256, nb2 + (size_t)l * 128,
        pc, pdelta, xn, pn, last ? 0 : 1);

    xc = xn;
    pc = pn;
  }
}

// Round 4
// 1605.794 us; speedup vs baseline: 1.5836x; 1.4147x over previous
//
#include <hip/hip_runtime.h>
#include <hip/hip_bf16.h>
#include <math.h>

#define N_NODES 50000
#define N_EDGES 500000
#define H 128
#define NL 3
#define SCAN_B 256
#define NCHUNK ((N_NODES + SCAN_B - 1) / SCAN_B)

typedef short short8v __attribute__((ext_vector_type(8)));
typedef float f32x4 __attribute__((ext_vector_type(4)));
typedef unsigned short ushort8v __attribute__((ext_vector_type(8)));
typedef unsigned short ushort4v __attribute__((ext_vector_type(4)));

__device__ __forceinline__ unsigned short f2b(float f) {
  __hip_bfloat16 h = __float2bfloat16(f);
  return __builtin_bit_cast(unsigned short, h);
}
__device__ __forceinline__ float b2f(unsigned short s) {
  unsigned u = (unsigned)s << 16;
  return __builtin_bit_cast(float, u);
}

// ---------------- counting sort of edges by dst ----------------

__global__ void k_deg_i(const int* __restrict__ dst, int* __restrict__ degC) {
  int e = blockIdx.x * blockDim.x + threadIdx.x;
  if (e < N_EDGES) atomicAdd(&degC[dst[e]], 1);
}

__global__ void k_inv(const int* __restrict__ degC, float* __restrict__ invd) {
  int i = blockIdx.x * blockDim.x + threadIdx.x;
  if (i < N_NODES) invd[i] = 1.0f / fmaxf((float)degC[i], 1.0f);
}

__global__ void k_scan1(const int* __restrict__ degC, int* __restrict__ cursor,
                        int* __restrict__ chunkSum) {
  __shared__ int s[SCAN_B];
  int t = threadIdx.x, i = blockIdx.x * SCAN_B + t;
  int v = (i < N_NODES) ? degC[i] : 0;
  s[t] = v;
  __syncthreads();
  for (int o = 1; o < SCAN_B; o <<= 1) {
    int u = (t >= o) ? s[t - o] : 0;
    __syncthreads();
    s[t] += u;
    __syncthreads();
  }
  if (i < N_NODES) cursor[i] = s[t] - v;
  if (t == SCAN_B - 1) chunkSum[blockIdx.x] = s[t];
}

__global__ void k_scan2(int* __restrict__ chunkSum) {
  __shared__ int s[SCAN_B];
  int t = threadIdx.x;
  int v = (t < NCHUNK) ? chunkSum[t] : 0;
  s[t] = v;
  __syncthreads();
  for (int o = 1; o < SCAN_B; o <<= 1) {
    int u = (t >= o) ? s[t - o] : 0;
    __syncthreads();
    s[t] += u;
    __syncthreads();
  }
  if (t < NCHUNK) chunkSum[t] = s[t] - v;
}

__global__ void k_scan3(int* __restrict__ cursor, const int* __restrict__ chunkSum) {
  int i = blockIdx.x * SCAN_B + threadIdx.x;
  if (i < N_NODES) cursor[i] += chunkSum[blockIdx.x];
}

__global__ void k_scatter_sort(const int* __restrict__ dst, int* __restrict__ cursor,
                               int* __restrict__ sorted) {
  int e = blockIdx.x * blockDim.x + threadIdx.x;
  if (e < N_EDGES) {
    int p = atomicAdd(&cursor[dst[e]], 1);
    sorted[p] = e;
  }
}

// ---------------- one-time permutation of edge data into dst-sorted order ----------------
// eattrS[slot] = bf16(eattr[sorted[slot]]); srcS/dstS[slot] = src/dst[sorted[slot]]

__global__ void k_perm(const float* __restrict__ eattr, const int* __restrict__ sorted,
                       const int* __restrict__ srcI, const int* __restrict__ dstI,
                       unsigned short* __restrict__ eattrS,
                       int* __restrict__ srcS, int* __restrict__ dstS) {
  int g = blockIdx.x * 16 + (threadIdx.x >> 4);   // slot
  int seg = threadIdx.x & 15;                     // 8-channel segment
  if (g < N_EDGES) {
    int eid = sorted[g];
    const float* ep = eattr + (size_t)eid * H + seg * 8;
    float4 p0 = *(const float4*)ep;
    float4 p1 = *(const float4*)(ep + 4);
    ushort8v v;
    v[0] = f2b(p0.x); v[1] = f2b(p0.y); v[2] = f2b(p0.z); v[3] = f2b(p0.w);
    v[4] = f2b(p1.x); v[5] = f2b(p1.y); v[6] = f2b(p1.z); v[7] = f2b(p1.w);
    *(ushort8v*)&eattrS[(size_t)g * H + seg * 8] = v;
    if (seg == 0) { srcS[g] = srcI[eid]; dstS[g] = dstI[eid]; }
  }
}

// ---------------- fp32 -> bf16 conversions ----------------

__global__ void k_cvt_x(const float* __restrict__ x, unsigned short* __restrict__ xb, int n4) {
  int i = blockIdx.x * blockDim.x + threadIdx.x;
  if (i < n4) {
    float4 v = ((const float4*)x)[i];
    ushort4v o;
    o[0] = f2b(v.x); o[1] = f2b(v.y); o[2] = f2b(v.z); o[3] = f2b(v.w);
    ((ushort4v*)xb)[i] = o;
  }
}

// src [L][K][N] fp32 -> dst [L][N][K] bf16
__global__ void k_cvt_wt(const float* __restrict__ src, unsigned short* __restrict__ dst,
                         int K, int N, int total) {
  int i = blockIdx.x * blockDim.x + threadIdx.x;
  if (i < total) {
    int l = i / (K * N);
    int rem = i - l * K * N;
    int k = rem / N;
    int n = rem - k * N;
    dst[((size_t)l * N + n) * K + k] = f2b(src[i]);
  }
}

// ---------------- MFMA helpers ----------------
// C/D layout: D[wv*16 + quad*4 + r][nt*16 + (lane&15)] = acc[nt][r]

// 64-K-chunk B staging (pitch 72) -- used by k_xab / k_node (R1-proven form)
#define MFMA_STEP(AP, APITCH, AKOFF, ACCN)                                         \
  { _Pragma("unroll")                                                              \
    for (int ks = 0; ks < 2; ++ks) {                                               \
      short8v af_ = *(const short8v*)&AP[(wv * 16 + ln15) * APITCH + (AKOFF) + ks * 32 + quad * 8]; \
      _Pragma("unroll")                                                            \
      for (int nt = 0; nt < 8; ++nt) {                                             \
        short8v bf_ = *(const short8v*)&sB[(nt * 16 + ln15) * 72 + ks * 32 + quad * 8]; \
        ACCN[nt] = __builtin_amdgcn_mfma_f32_16x16x32_bf16(af_, bf_, ACCN[nt], 0, 0, 0); \
      } } }

#define STAGE_B(EXPR)                                                              \
  { _Pragma("unroll")                                                              \
    for (int i_ = 0; i_ < 4; ++i_) {                                               \
      int flat_ = tid + i_ * 256;                                                  \
      int n = flat_ >> 3, seg = flat_ & 7;                                         \
      *(float4*)&sB[n * 72 + seg * 8] = *(const float4*)&(EXPR);                   \
    } }

// full 128x128 weight stage (pitch 136) -- used by k_edge_m
#define STAGE128(BASE, PITCH, KOFF)                                                \
  { _Pragma("unroll")                                                              \
    for (int i_ = 0; i_ < 8; ++i_) {                                               \
      int flat_ = tid + i_ * 256;                                                  \
      int n_ = flat_ >> 4, sg_ = flat_ & 15;                                       \
      *(float4*)&sB[n_ * 136 + sg_ * 8] =                                          \
          *(const float4*)&(BASE)[(size_t)n_ * (PITCH) + (KOFF) + sg_ * 8];        \
    } }

// full-K (128) MFMA: A from LDS (pitch 136), B from sB (pitch 136)
#define MFMA_FULL(AP, ACCN)                                                        \
  { _Pragma("unroll")                                                              \
    for (int c_ = 0; c_ < 2; ++c_)                                                 \
      _Pragma("unroll")                                                            \
      for (int ks_ = 0; ks_ < 2; ++ks_) {                                          \
        short8v af_ = *(const short8v*)&AP[(wv * 16 + ln15) * 136 + c_ * 64 + ks_ * 32 + quad * 8]; \
        _Pragma("unroll")                                                          \
        for (int nt_ = 0; nt_ < 8; ++nt_) {                                        \
          short8v bf_ = *(const short8v*)&sB[(nt_ * 16 + ln15) * 136 + c_ * 64 + ks_ * 32 + quad * 8]; \
          ACCN[nt_] = __builtin_amdgcn_mfma_f32_16x16x32_bf16(af_, bf_, ACCN[nt_], 0, 0, 0); \
        } } }

// ---------------- per-layer node-side precompute: XAB = x @ [W1a|W1b] (+mb1 folded) ----

__launch_bounds__(256, 4)
__global__ void k_xab(const unsigned short* __restrict__ xb,
                      const unsigned short* __restrict__ mW1t,  // [128n][384k]
                      const float* __restrict__ mb1,
                      unsigned short* __restrict__ xab)
{
  __shared__ unsigned short sB[128 * 72];
  const int tid = threadIdx.x;
  const int n0 = blockIdx.x * 64;
  const int wv = tid >> 6, lane = tid & 63, quad = lane >> 4, ln15 = lane & 15;
  const int arow = min(n0 + wv * 16 + ln15, N_NODES - 1);

  short8v afr[2][2];
#pragma unroll
  for (int c = 0; c < 2; ++c)
#pragma unroll
    for (int ks = 0; ks < 2; ++ks)
      afr[c][ks] = *(const short8v*)&xb[(size_t)arow * H + c * 64 + ks * 32 + quad * 8];

  for (int h = 0; h < 2; ++h) {
    f32x4 acc[8];
#pragma unroll
    for (int nt = 0; nt < 8; ++nt) acc[nt] = (f32x4){0.f, 0.f, 0.f, 0.f};
    for (int c = 0; c < 2; ++c) {
      STAGE_B(mW1t[(size_t)n * 384 + h * 128 + c * 64 + seg * 8])
      __syncthreads();
#pragma unroll
      for (int ks = 0; ks < 2; ++ks) {
#pragma unroll
        for (int nt = 0; nt < 8; ++nt) {
          short8v bf = *(const short8v*)&sB[(nt * 16 + ln15) * 72 + ks * 32 + quad * 8];
          acc[nt] = __builtin_amdgcn_mfma_f32_16x16x32_bf16(afr[c][ks], bf, acc[nt], 0, 0, 0);
        }
      }
      __syncthreads();
    }
#pragma unroll
    for (int nt = 0; nt < 8; ++nt) {
      int col = nt * 16 + ln15;
      float bb = (h == 0) ? mb1[col] : 0.f;
#pragma unroll
      for (int r = 0; r < 4; ++r) {
        int row = n0 + wv * 16 + quad * 4 + r;
        if (row < N_NODES)
          xab[(size_t)row * 256 + h * 128 + col] = f2b(acc[nt][r] + bb);
      }
    }
  }
}

// ---------------- edge message kernel: m + w, no scatters ----------------

__launch_bounds__(256, 3)
__global__ void k_edge_m(const unsigned short* __restrict__ xab,    // [N][256] bf16
                         const unsigned short* __restrict__ eattrS, // [E][128] bf16 sorted
                         const int* __restrict__ srcS,
                         const int* __restrict__ dstS,
                         const unsigned short* __restrict__ mW1t,   // [128][384]
                         const unsigned short* __restrict__ mW2t,   // [128][128]
                         const float* __restrict__ mb2,
                         const unsigned short* __restrict__ aW1t,   // [256][128]
                         const float* __restrict__ ab1,
                         const float* __restrict__ aW2, const float* __restrict__ ab2,
                         unsigned short* __restrict__ mS,           // [E][128] bf16 out
                         float* __restrict__ wS,                    // [E] out
                         int do_m)
{
  __shared__ unsigned short sM[64 * 136];   // XA+XB -> h1 -> m
  __shared__ unsigned short sB[128 * 136];  // one full 128x128 weight
  __shared__ int sSrc[64], sDst[64];
  __shared__ float sW[64];

  const int tid = threadIdx.x;
  // bijective XCD-aware swizzle (xab gathers of neighboring tiles share L2)
  const int nwg = gridDim.x;
  const int q_ = nwg >> 3, r_ = nwg & 7;
  const int xcd = blockIdx.x & 7, bidx = blockIdx.x >> 3;
  const int bid = (xcd < r_ ? xcd * (q_ + 1) : r_ * (q_ + 1) + (xcd - r_) * q_) + bidx;
  const int e0 = bid * 64;

  if (tid < 64) {
    int idx = min(e0 + tid, N_EDGES - 1);
    sSrc[tid] = srcS[idx]; sDst[tid] = dstS[idx];
  }
  __syncthreads();                                              // B1

  const int wv = tid >> 6, lane = tid & 63, quad = lane >> 4, ln15 = lane & 15;

  // eattr A-fragments: LINEAR bf16 reads
  const int slotA = min(e0 + wv * 16 + ln15, N_EDGES - 1);
  short8v afr[2][2];
#pragma unroll
  for (int c = 0; c < 2; ++c)
#pragma unroll
    for (int ks = 0; ks < 2; ++ks)
      afr[c][ks] = *(const short8v*)&eattrS[(size_t)slotA * H + c * 64 + ks * 32 + quad * 8];

  // assemble XA[dst] + XB[src] into sM
#pragma unroll
  for (int i_ = 0; i_ < 4; ++i_) {
    int flat = tid + i_ * 256;
    int row = flat >> 4, sg = flat & 15;
    ushort8v a = *(const ushort8v*)&xab[(size_t)sDst[row] * 256 + sg * 8];
    ushort8v b = *(const ushort8v*)&xab[(size_t)sSrc[row] * 256 + 128 + sg * 8];
    ushort8v o;
#pragma unroll
    for (int j = 0; j < 8; ++j) o[j] = f2b(b2f(a[j]) + b2f(b[j]));
    *(ushort8v*)&sM[row * 136 + sg * 8] = o;
  }

  STAGE128(mW1t, 384, 256)                                      // W1c whole
  __syncthreads();                                              // B2

  f32x4 acc[8];
#pragma unroll
  for (int nt = 0; nt < 8; ++nt) acc[nt] = (f32x4){0.f, 0.f, 0.f, 0.f};

  // GEMM1c: eattr @ W1c (A in regs)
#pragma unroll
  for (int c = 0; c < 2; ++c)
#pragma unroll
    for (int ks = 0; ks < 2; ++ks) {
#pragma unroll
      for (int nt = 0; nt < 8; ++nt) {
        short8v bf = *(const short8v*)&sB[(nt * 16 + ln15) * 136 + c * 64 + ks * 32 + quad * 8];
        acc[nt] = __builtin_amdgcn_mfma_f32_16x16x32_bf16(afr[c][ks], bf, acc[nt], 0, 0, 0);
      }
    }

  // h1 = relu(acc + (XA+XB+mb1)) -- rmw of own C-elements, no cross-thread hazard
#pragma unroll
  for (int nt = 0; nt < 8; ++nt) {
    int col = nt * 16 + ln15;
#pragma unroll
    for (int r = 0; r < 4; ++r) {
      int row = wv * 16 + quad * 4 + r;
      float xv = b2f(sM[row * 136 + col]);
      sM[row * 136 + col] = f2b(fmaxf(acc[nt][r] + xv, 0.f));
      acc[nt][r] = 0.f;
    }
  }
  __syncthreads();                                              // B3: h1 visible, sB free

  STAGE128(mW2t, 128, 0)
  __syncthreads();                                              // B4

  MFMA_FULL(sM, acc)                                            // GEMM2: h1 @ W2
  __syncthreads();                                              // B5: GEMM2 A-reads done

  // m = acc + mb2 -> sM; stage aW1 h0 concurrently
#pragma unroll
  for (int nt = 0; nt < 8; ++nt) {
    int col = nt * 16 + ln15;
    float bb = mb2[col];
#pragma unroll
    for (int r = 0; r < 4; ++r) {
      int row = wv * 16 + quad * 4 + r;
      sM[row * 136 + col] = f2b(acc[nt][r] + bb);
    }
  }
  STAGE128(aW1t, 128, 0)
  __syncthreads();                                              // B6: m visible, sB=aW1h0

  float wp0 = 0.f, wp1 = 0.f, wp2 = 0.f, wp3 = 0.f;
  {
#pragma unroll
    for (int nt = 0; nt < 8; ++nt) acc[nt] = (f32x4){0.f, 0.f, 0.f, 0.f};
    MFMA_FULL(sM, acc)
#pragma unroll
    for (int nt = 0; nt < 8; ++nt) {
      int col = nt * 16 + ln15;
      float bb = ab1[col], a2 = aW2[col];
      wp0 += fmaxf(acc[nt][0] + bb, 0.f) * a2;
      wp1 += fmaxf(acc[nt][1] + bb, 0.f) * a2;
      wp2 += fmaxf(acc[nt][2] + bb, 0.f) * a2;
      wp3 += fmaxf(acc[nt][3] + bb, 0.f) * a2;
    }
  }
  __syncthreads();                                              // B7: h0 MFMAs done
  STAGE128((aW1t + (size_t)128 * 128), 128, 0)
  __syncthreads();                                              // B8: sB=aW1h1
  {
#pragma unroll
    for (int nt = 0; nt < 8; ++nt) acc[nt] = (f32x4){0.f, 0.f, 0.f, 0.f};
    MFMA_FULL(sM, acc)
#pragma unroll
    for (int nt = 0; nt < 8; ++nt) {
      int col = 128 + nt * 16 + ln15;
      float bb = ab1[col], a2 = aW2[col];
      wp0 += fmaxf(acc[nt][0] + bb, 0.f) * a2;
      wp1 += fmaxf(acc[nt][1] + bb, 0.f) * a2;
      wp2 += fmaxf(acc[nt][2] + bb, 0.f) * a2;
      wp3 += fmaxf(acc[nt][3] + bb, 0.f) * a2;
    }
  }
#pragma unroll
  for (int m = 1; m <= 8; m <<= 1) {
    wp0 += __shfl_xor(wp0, m, 64);
    wp1 += __shfl_xor(wp1, m, 64);
    wp2 += __shfl_xor(wp2, m, 64);
    wp3 += __shfl_xor(wp3, m, 64);
  }
  if (ln15 == 0) {
    float b2 = ab2[0];
    sW[wv * 16 + quad * 4 + 0] = wp0 + b2;
    sW[wv * 16 + quad * 4 + 1] = wp1 + b2;
    sW[wv * 16 + quad * 4 + 2] = wp2 + b2;
    sW[wv * 16 + quad * 4 + 3] = wp3 + b2;
  }

  // store m (sM stable since B6), coalesced 16B chunks
  if (do_m) {
#pragma unroll
    for (int i_ = 0; i_ < 4; ++i_) {
      int flat = tid + i_ * 256;
      int row = flat >> 4, sg = flat & 15;
      int slot = e0 + row;
      if (slot < N_EDGES)
        *(ushort8v*)&mS[(size_t)slot * H + sg * 8] =
            *(const ushort8v*)&sM[row * 136 + sg * 8];
    }
  }
  __syncthreads();                                              // B9: sW visible
  if (tid < 64 && e0 + tid < N_EDGES) wS[e0 + tid] = sW[tid];
}

// ---------------- segmented reduce: intra + pdelta (CSR ranges, no atomics) ----------------

__launch_bounds__(256, 8)
__global__ void k_seg(const unsigned short* __restrict__ mS,
                      const float* __restrict__ wS,
                      const int* __restrict__ srcS,
                      const float* __restrict__ pos,
                      const int* __restrict__ cursor,   // cursor[n] = exclusive end of node n
                      float* __restrict__ intra,
                      float* __restrict__ pdelta,
                      int do_intra)
{
  const int n0 = blockIdx.x * 64;
  const int tid = threadIdx.x;

  if (tid < 128) {
    if (!do_intra) return;
    const int f = tid;
    for (int j = 0; j < 64; ++j) {
      int n = n0 + j;
      if (n >= N_NODES) break;
      int rs = (n == 0) ? 0 : cursor[n - 1];
      int re = cursor[n];
      float a = 0.f;
      for (int s = rs; s < re; ++s) a += b2f(mS[(size_t)s * H + f]);
      intra[(size_t)n * H + f] = a;
    }
  } else {
    for (int idx = tid - 128; idx < 192; idx += 128) {
      int n = n0 + idx / 3, c = idx % 3;
      if (n >= N_NODES) continue;
      int rs = (n == 0) ? 0 : cursor[n - 1];
      int re = cursor[n];
      float pd = pos[n * 3 + c];
      float px = pos[n * 3 + 0], py = pos[n * 3 + 1], pz = pos[n * 3 + 2];
      float a = 0.f;
      for (int s = rs; s < re; ++s) {
        int sn = srcS[s];
        float rx = pos[sn * 3 + 0] - px;
        float ry = pos[sn * 3 + 1] - py;
        float rz = pos[sn * 3 + 2] - pz;
        float dist = sqrtf(rx * rx + ry * ry + rz * rz);
        float rc = (c == 0) ? rx : ((c == 1) ? ry : rz);
        a += wS[s] * rc / dist;
      }
      (void)pd;
      pdelta[n * 3 + c] = a;
    }
  }
}

// ---------------- node kernel (R1-proven form) ----------------

__launch_bounds__(256, 3)
__global__ void k_node(const unsigned short* __restrict__ xb,
                       const float* __restrict__ intra,
                       const float* __restrict__ invd,
                       const unsigned short* __restrict__ nW1t, const float* __restrict__ nb1,
                       const unsigned short* __restrict__ nW2t, const float* __restrict__ nb2,
                       const float* __restrict__ pos_in,
                       const float* __restrict__ pdelta,
                       unsigned short* __restrict__ xb_out,
                       float* __restrict__ pos_out,
                       int compute_x)
{
  __shared__ unsigned short sA[64 * 72];
  __shared__ unsigned short sB[128 * 72];
  __shared__ unsigned short sH[64 * 136];
  const int tid = threadIdx.x;
  const int n0 = blockIdx.x * 64;

  if (tid < 192) {
    int n = n0 + tid / 3, cc = tid % 3;
    if (n < N_NODES)
      pos_out[n * 3 + cc] = pos_in[n * 3 + cc] + pdelta[n * 3 + cc] * invd[n];
  }
  if (!compute_x) return;

  const int wv = tid >> 6, lane = tid & 63, quad = lane >> 4, ln15 = lane & 15;

  f32x4 xacc[8];
#pragma unroll
  for (int nt = 0; nt < 8; ++nt) xacc[nt] = (f32x4){0.f, 0.f, 0.f, 0.f};

  f32x4 acc[8];
  for (int h = 0; h < 2; ++h) {
#pragma unroll
    for (int nt = 0; nt < 8; ++nt) acc[nt] = (f32x4){0.f, 0.f, 0.f, 0.f};
    for (int c = 0; c < 4; ++c) {
#pragma unroll
      for (int i_ = 0; i_ < 2; ++i_) {
        int flat_ = tid + i_ * 256;
        int row = flat_ >> 3, seg = flat_ & 7;
        int n = min(n0 + row, N_NODES - 1);
        if (c < 2) {
          *(float4*)&sA[row * 72 + seg * 8] =
              *(const float4*)&xb[(size_t)n * H + c * 64 + seg * 8];
        } else {
          const float* ip = intra + (size_t)n * H + (c - 2) * 64 + seg * 8;
          float iv = invd[n];
          float4 p0 = *(const float4*)ip;
          float4 p1 = *(const float4*)(ip + 4);
          ushort8v v;
          v[0] = f2b(p0.x * iv); v[1] = f2b(p0.y * iv);
          v[2] = f2b(p0.z * iv); v[3] = f2b(p0.w * iv);
          v[4] = f2b(p1.x * iv); v[5] = f2b(p1.y * iv);
          v[6] = f2b(p1.z * iv); v[7] = f2b(p1.w * iv);
          *(ushort8v*)&sA[row * 72 + seg * 8] = v;
        }
      }
      STAGE_B(nW1t[((size_t)h * 128 + n) * 256 + c * 64 + seg * 8])
      __syncthreads();
      MFMA_STEP(sA, 72, 0, acc)
      __syncthreads();
    }
#pragma unroll
    for (int nt = 0; nt < 8; ++nt) {
      int col = nt * 16 + ln15;
      float bb = nb1[h * 128 + col];
#pragma unroll
      for (int r = 0; r < 4; ++r) {
        int row = wv * 16 + quad * 4 + r;
        sH[row * 136 + col] = f2b(fmaxf(acc[nt][r] + bb, 0.f));
      }
    }
    __syncthreads();
    for (int c2 = 0; c2 < 2; ++c2) {
      STAGE_B(nW2t[(size_t)n * 256 + h * 128 + c2 * 64 + seg * 8])
      __syncthreads();
      MFMA_STEP(sH, 136, c2 * 64, xacc)
      __syncthreads();
    }
  }
#pragma unroll
  for (int nt = 0; nt < 8; ++nt) {
    int col = nt * 16 + ln15;
    float bb = nb2[col];
#pragma unroll
    for (int r = 0; r < 4; ++r) {
      int row = n0 + wv * 16 + quad * 4 + r;
      if (row < N_NODES)
        xb_out[(size_t)row * H + col] = f2b(xacc[nt][r] + bb);
    }
  }
}

extern "C" void kernel_launch(void* const* d_in, const int* in_sizes, int n_in,
                              void* d_out, int out_size, void* d_ws, size_t ws_size,
                              hipStream_t stream) {
  const float* x0    = (const float*)d_in[0];
  const int*   eidx  = (const int*)d_in[1];
  const float* eattr = (const float*)d_in[2];
  const float* pos0  = (const float*)d_in[3];
  const float* mW1 = (const float*)d_in[4];
  const float* mb1 = (const float*)d_in[5];
  const float* mW2 = (const float*)d_in[6];
  const float* mb2 = (const float*)d_in[7];
  const float* aW1 = (const float*)d_in[8];
  const float* ab1 = (const float*)d_in[9];
  const float* aW2 = (const float*)d_in[10];
  const float* ab2 = (const float*)d_in[11];
  const float* nW1 = (const float*)d_in[12];
  const float* nb1 = (const float*)d_in[13];
  const float* nW2 = (const float*)d_in[14];
  const float* nb2 = (const float*)d_in[15];
  const int* srcI = eidx;
  const int* dstI = eidx + N_EDGES;

  char* wsb = (char*)d_ws;
  int*   degC    = (int*)wsb;                     wsb += (size_t)N_NODES * 4;
  int*   cursor  = (int*)wsb;                     wsb += (size_t)N_NODES * 4;
  int*   chunkS  = (int*)wsb;                     wsb += 256 * 4;
  int*   sorted  = (int*)wsb;                     wsb += (size_t)N_EDGES * 4;
  float* invd    = (float*)wsb;                   wsb += (size_t)N_NODES * 4;
  float* pdelta  = (float*)wsb;                   wsb += (size_t)3 * N_NODES * 4;
  float* pos_a   = (float*)wsb;                   wsb += (size_t)3 * N_NODES * 4;
  float* pos_b   = (float*)wsb;                   wsb += (size_t)3 * N_NODES * 4;
  float* intra   = (float*)wsb;                   wsb += (size_t)N_NODES * H * 4;
  unsigned short* xb0  = (unsigned short*)wsb;    wsb += (size_t)N_NODES * H * 2;
  unsigned short* xb_a = (unsigned short*)wsb;    wsb += (size_t)N_NODES * H * 2;
  unsigned short* xb_b = (unsigned short*)wsb;    wsb += (size_t)N_NODES * H * 2;
  unsigned short* xabW = (unsigned short*)wsb;    wsb += (size_t)N_NODES * 256 * 2;
  unsigned short* eattrS = (unsigned short*)wsb;  wsb += (size_t)N_EDGES * H * 2;
  unsigned short* mS   = (unsigned short*)wsb;    wsb += (size_t)N_EDGES * H * 2;
  int*   srcS    = (int*)wsb;                     wsb += (size_t)N_EDGES * 4;
  int*   dstS    = (int*)wsb;                     wsb += (size_t)N_EDGES * 4;
  float* wS      = (float*)wsb;                   wsb += (size_t)N_EDGES * 4;
  unsigned short* mW1t = (unsigned short*)wsb;    wsb += (size_t)NL * 128 * 384 * 2;
  unsigned short* mW2t = (unsigned short*)wsb;    wsb += (size_t)NL * 128 * 128 * 2;
  unsigned short* aW1t = (unsigned short*)wsb;    wsb += (size_t)NL * 256 * 128 * 2;
  unsigned short* nW1t = (unsigned short*)wsb;    wsb += (size_t)NL * 256 * 256 * 2;
  unsigned short* nW2t = (unsigned short*)wsb;    wsb += (size_t)NL * 128 * 256 * 2;

  // counting sort of edges by dst (every launch; ws is re-poisoned)
  hipMemsetAsync(degC, 0, N_NODES * sizeof(int), stream);
  k_deg_i<<<(N_EDGES + 255) / 256, 256, 0, stream>>>(dstI, degC);
  k_inv<<<(N_NODES + 255) / 256, 256, 0, stream>>>(degC, invd);
  k_scan1<<<NCHUNK, SCAN_B, 0, stream>>>(degC, cursor, chunkS);
  k_scan2<<<1, SCAN_B, 0, stream>>>(chunkS);
  k_scan3<<<NCHUNK, SCAN_B, 0, stream>>>(cursor, chunkS);
  k_scatter_sort<<<(N_EDGES + 255) / 256, 256, 0, stream>>>(dstI, cursor, sorted);
  // NOTE: after k_scatter_sort, cursor[n] == exclusive end of node n's slot range

  // one-time: permute eattr/src/dst into dst-sorted slot order (bf16)
  k_perm<<<(N_EDGES * 16 + 255) / 256, 256, 0, stream>>>(
      eattr, sorted, srcI, dstI, eattrS, srcS, dstS);

  // bf16 conversions
  {
    int n4 = N_NODES * H / 4;
    k_cvt_x<<<(n4 + 255) / 256, 256, 0, stream>>>(x0, xb0, n4);
    int t1 = NL * 384 * 128;
    k_cvt_wt<<<(t1 + 255) / 256, 256, 0, stream>>>(mW1, mW1t, 384, 128, t1);
    int t2 = NL * 128 * 128;
    k_cvt_wt<<<(t2 + 255) / 256, 256, 0, stream>>>(mW2, mW2t, 128, 128, t2);
    int t3 = NL * 128 * 256;
    k_cvt_wt<<<(t3 + 255) / 256, 256, 0, stream>>>(aW1, aW1t, 128, 256, t3);
    int t4 = NL * 256 * 256;
    k_cvt_wt<<<(t4 + 255) / 256, 256, 0, stream>>>(nW1, nW1t, 256, 256, t4);
    int t5 = NL * 256 * 128;
    k_cvt_wt<<<(t5 + 255) / 256, 256, 0, stream>>>(nW2, nW2t, 256, 128, t5);
  }

  const unsigned short* xc = xb0;
  const float* pc = pos0;
  float* pos_out_final = (float*)d_out;

  for (int l = 0; l < NL; ++l) {
    int last = (l == NL - 1);

    k_xab<<<(N_NODES + 63) / 64, 256, 0, stream>>>(
        xc, mW1t + (size_t)l * 128 * 384, mb1 + (size_t)l * 128, xabW);

    k_edge_m<<<(N_EDGES + 63) / 64, 256, 0, stream>>>(
        xabW, eattrS, srcS, dstS,
        mW1t + (size_t)l * 128 * 384,
        mW2t + (size_t)l * 128 * 128, mb2 + (size_t)l * 128,
        aW1t + (size_t)l * 256 * 128, ab1 + (size_t)l * 256,
        aW2 + (size_t)l * 256, ab2 + l,
        mS, wS, last ? 0 : 1);

    k_seg<<<(N_NODES + 63) / 64, 256, 0, stream>>>(
        mS, wS, srcS, pc, cursor, intra, pdelta, last ? 0 : 1);

    float* pn = last ? pos_out_final : (l == 0 ? pos_a : pos_b);
    unsigned short* xn = (l == 0) ? xb_a : xb_b;
    k_node<<<(N_NODES + 63) / 64, 256, 0, stream>>>(
        xc, intra, invd,
        nW1t + (size_t)l * 256 * 256, nb1 + (size_t)l * 256,
        nW2t + (size_t)l * 128 * 256, nb2 + (size_t)l * 128,
        pc, pdelta, xn, pn, last ? 0 : 1);

    xc = xn;
    pc = pn;
  }
}

// Round 5
// 1179.142 us; speedup vs baseline: 2.1566x; 1.3618x over previous
//
#include <hip/hip_runtime.h>
#include <hip/hip_bf16.h>
#include <math.h>

#define N_NODES 50000
#define N_EDGES 500000
#define H 128
#define NL 3
#define SCAN_B 256
#define NCHUNK ((N_NODES + SCAN_B - 1) / SCAN_B)

typedef short short8v __attribute__((ext_vector_type(8)));
typedef float f32x4 __attribute__((ext_vector_type(4)));
typedef unsigned short ushort8v __attribute__((ext_vector_type(8)));
typedef unsigned short ushort4v __attribute__((ext_vector_type(4)));

__device__ __forceinline__ unsigned short f2b(float f) {
  __hip_bfloat16 h = __float2bfloat16(f);
  return __builtin_bit_cast(unsigned short, h);
}
__device__ __forceinline__ float b2f(unsigned short s) {
  unsigned u = (unsigned)s << 16;
  return __builtin_bit_cast(float, u);
}

// ---------------- counting sort of edges by dst ----------------

__global__ void k_deg_i(const int* __restrict__ dst, int* __restrict__ degC) {
  int e = blockIdx.x * blockDim.x + threadIdx.x;
  if (e < N_EDGES) atomicAdd(&degC[dst[e]], 1);
}

__global__ void k_inv(const int* __restrict__ degC, float* __restrict__ invd) {
  int i = blockIdx.x * blockDim.x + threadIdx.x;
  if (i < N_NODES) invd[i] = 1.0f / fmaxf((float)degC[i], 1.0f);
}

__global__ void k_scan1(const int* __restrict__ degC, int* __restrict__ cursor,
                        int* __restrict__ chunkSum) {
  __shared__ int s[SCAN_B];
  int t = threadIdx.x, i = blockIdx.x * SCAN_B + t;
  int v = (i < N_NODES) ? degC[i] : 0;
  s[t] = v;
  __syncthreads();
  for (int o = 1; o < SCAN_B; o <<= 1) {
    int u = (t >= o) ? s[t - o] : 0;
    __syncthreads();
    s[t] += u;
    __syncthreads();
  }
  if (i < N_NODES) cursor[i] = s[t] - v;
  if (t == SCAN_B - 1) chunkSum[blockIdx.x] = s[t];
}

__global__ void k_scan2(int* __restrict__ chunkSum) {
  __shared__ int s[SCAN_B];
  int t = threadIdx.x;
  int v = (t < NCHUNK) ? chunkSum[t] : 0;
  s[t] = v;
  __syncthreads();
  for (int o = 1; o < SCAN_B; o <<= 1) {
    int u = (t >= o) ? s[t - o] : 0;
    __syncthreads();
    s[t] += u;
    __syncthreads();
  }
  if (t < NCHUNK) chunkSum[t] = s[t] - v;
}

__global__ void k_scan3(int* __restrict__ cursor, const int* __restrict__ chunkSum) {
  int i = blockIdx.x * SCAN_B + threadIdx.x;
  if (i < N_NODES) cursor[i] += chunkSum[blockIdx.x];
}

__global__ void k_scatter_sort(const int* __restrict__ dst, int* __restrict__ cursor,
                               int* __restrict__ sorted) {
  int e = blockIdx.x * blockDim.x + threadIdx.x;
  if (e < N_EDGES) {
    int p = atomicAdd(&cursor[dst[e]], 1);
    sorted[p] = e;
  }
}

// ---------------- one-time permutation of edge data into dst-sorted order ----------------

__global__ void k_perm(const float* __restrict__ eattr, const int* __restrict__ sorted,
                       const int* __restrict__ srcI, const int* __restrict__ dstI,
                       unsigned short* __restrict__ eattrS,
                       int* __restrict__ srcS, int* __restrict__ dstS) {
  int g = blockIdx.x * 16 + (threadIdx.x >> 4);   // slot
  int seg = threadIdx.x & 15;                     // 8-channel segment
  if (g < N_EDGES) {
    int eid = sorted[g];
    const float* ep = eattr + (size_t)eid * H + seg * 8;
    float4 p0 = *(const float4*)ep;
    float4 p1 = *(const float4*)(ep + 4);
    ushort8v v;
    v[0] = f2b(p0.x); v[1] = f2b(p0.y); v[2] = f2b(p0.z); v[3] = f2b(p0.w);
    v[4] = f2b(p1.x); v[5] = f2b(p1.y); v[6] = f2b(p1.z); v[7] = f2b(p1.w);
    *(ushort8v*)&eattrS[(size_t)g * H + seg * 8] = v;
    if (seg == 0) { srcS[g] = srcI[eid]; dstS[g] = dstI[eid]; }
  }
}

// ---------------- fp32 -> bf16 conversions ----------------

__global__ void k_cvt_x(const float* __restrict__ x, unsigned short* __restrict__ xb, int n4) {
  int i = blockIdx.x * blockDim.x + threadIdx.x;
  if (i < n4) {
    float4 v = ((const float4*)x)[i];
    ushort4v o;
    o[0] = f2b(v.x); o[1] = f2b(v.y); o[2] = f2b(v.z); o[3] = f2b(v.w);
    ((ushort4v*)xb)[i] = o;
  }
}

// src [L][K][N] fp32 -> dst [L][N][K] bf16
__global__ void k_cvt_wt(const float* __restrict__ src, unsigned short* __restrict__ dst,
                         int K, int N, int total) {
  int i = blockIdx.x * blockDim.x + threadIdx.x;
  if (i < total) {
    int l = i / (K * N);
    int rem = i - l * K * N;
    int k = rem / N;
    int n = rem - k * N;
    dst[((size_t)l * N + n) * K + k] = f2b(src[i]);
  }
}

// ---------------- MFMA helpers ----------------
// C/D layout: D[wv*16 + quad*4 + r][nt*16 + (lane&15)] = acc[nt][r]

#define MFMA_STEP(AP, APITCH, AKOFF, ACCN)                                         \
  { _Pragma("unroll")                                                              \
    for (int ks = 0; ks < 2; ++ks) {                                               \
      short8v af_ = *(const short8v*)&AP[(wv * 16 + ln15) * APITCH + (AKOFF) + ks * 32 + quad * 8]; \
      _Pragma("unroll")                                                            \
      for (int nt = 0; nt < 8; ++nt) {                                             \
        short8v bf_ = *(const short8v*)&sB[(nt * 16 + ln15) * 72 + ks * 32 + quad * 8]; \
        ACCN[nt] = __builtin_amdgcn_mfma_f32_16x16x32_bf16(af_, bf_, ACCN[nt], 0, 0, 0); \
      } } }

#define STAGE_B(EXPR)                                                              \
  { _Pragma("unroll")                                                              \
    for (int i_ = 0; i_ < 4; ++i_) {                                               \
      int flat_ = tid + i_ * 256;                                                  \
      int n = flat_ >> 3, seg = flat_ & 7;                                         \
      *(float4*)&sB[n * 72 + seg * 8] = *(const float4*)&(EXPR);                   \
    } }

// full 128x128 weight stage (pitch 136) -- used by k_edge_m
#define STAGE128(BASE, PITCH, KOFF)                                                \
  { _Pragma("unroll")                                                              \
    for (int i_ = 0; i_ < 8; ++i_) {                                               \
      int flat_ = tid + i_ * 256;                                                  \
      int n_ = flat_ >> 4, sg_ = flat_ & 15;                                       \
      *(float4*)&sB[n_ * 136 + sg_ * 8] =                                          \
          *(const float4*)&(BASE)[(size_t)n_ * (PITCH) + (KOFF) + sg_ * 8];        \
    } }

// full-K (128) MFMA: A from LDS (pitch 136), B from sB (pitch 136)
#define MFMA_FULL(AP, ACCN)                                                        \
  { _Pragma("unroll")                                                              \
    for (int c_ = 0; c_ < 2; ++c_)                                                 \
      _Pragma("unroll")                                                            \
      for (int ks_ = 0; ks_ < 2; ++ks_) {                                          \
        short8v af_ = *(const short8v*)&AP[(wv * 16 + ln15) * 136 + c_ * 64 + ks_ * 32 + quad * 8]; \
        _Pragma("unroll")                                                          \
        for (int nt_ = 0; nt_ < 8; ++nt_) {                                        \
          short8v bf_ = *(const short8v*)&sB[(nt_ * 16 + ln15) * 136 + c_ * 64 + ks_ * 32 + quad * 8]; \
          ACCN[nt_] = __builtin_amdgcn_mfma_f32_16x16x32_bf16(af_, bf_, ACCN[nt_], 0, 0, 0); \
        } } }

// ---------------- per-layer node-side precompute: XAB = x @ [W1a|W1b] (+mb1 folded) ----

__launch_bounds__(256, 4)
__global__ void k_xab(const unsigned short* __restrict__ xb,
                      const unsigned short* __restrict__ mW1t,  // [128n][384k]
                      const float* __restrict__ mb1,
                      unsigned short* __restrict__ xab)
{
  __shared__ unsigned short sB[128 * 72];
  const int tid = threadIdx.x;
  const int n0 = blockIdx.x * 64;
  const int wv = tid >> 6, lane = tid & 63, quad = lane >> 4, ln15 = lane & 15;
  const int arow = min(n0 + wv * 16 + ln15, N_NODES - 1);

  short8v afr[2][2];
#pragma unroll
  for (int c = 0; c < 2; ++c)
#pragma unroll
    for (int ks = 0; ks < 2; ++ks)
      afr[c][ks] = *(const short8v*)&xb[(size_t)arow * H + c * 64 + ks * 32 + quad * 8];

  for (int h = 0; h < 2; ++h) {
    f32x4 acc[8];
#pragma unroll
    for (int nt = 0; nt < 8; ++nt) acc[nt] = (f32x4){0.f, 0.f, 0.f, 0.f};
    for (int c = 0; c < 2; ++c) {
      STAGE_B(mW1t[(size_t)n * 384 + h * 128 + c * 64 + seg * 8])
      __syncthreads();
#pragma unroll
      for (int ks = 0; ks < 2; ++ks) {
#pragma unroll
        for (int nt = 0; nt < 8; ++nt) {
          short8v bf = *(const short8v*)&sB[(nt * 16 + ln15) * 72 + ks * 32 + quad * 8];
          acc[nt] = __builtin_amdgcn_mfma_f32_16x16x32_bf16(afr[c][ks], bf, acc[nt], 0, 0, 0);
        }
      }
      __syncthreads();
    }
#pragma unroll
    for (int nt = 0; nt < 8; ++nt) {
      int col = nt * 16 + ln15;
      float bb = (h == 0) ? mb1[col] : 0.f;
#pragma unroll
      for (int r = 0; r < 4; ++r) {
        int row = n0 + wv * 16 + quad * 4 + r;
        if (row < N_NODES)
          xab[(size_t)row * 256 + h * 128 + col] = f2b(acc[nt][r] + bb);
      }
    }
  }
}

// ---------------- edge message kernel: m + w, no scatters ----------------

__launch_bounds__(256, 3)
__global__ void k_edge_m(const unsigned short* __restrict__ xab,    // [N][256] bf16
                         const unsigned short* __restrict__ eattrS, // [E][128] bf16 sorted
                         const int* __restrict__ srcS,
                         const int* __restrict__ dstS,
                         const unsigned short* __restrict__ mW1t,   // [128][384]
                         const unsigned short* __restrict__ mW2t,   // [128][128]
                         const float* __restrict__ mb2,
                         const unsigned short* __restrict__ aW1t,   // [256][128]
                         const float* __restrict__ ab1,
                         const float* __restrict__ aW2, const float* __restrict__ ab2,
                         unsigned short* __restrict__ mS,           // [E][128] bf16 out
                         float* __restrict__ wS,                    // [E] out
                         int do_m)
{
  __shared__ unsigned short sM[64 * 136];   // XA+XB -> h1 -> m
  __shared__ unsigned short sB[128 * 136];  // one full 128x128 weight
  __shared__ int sSrc[64], sDst[64];
  __shared__ float sW[64];

  const int tid = threadIdx.x;
  const int nwg = gridDim.x;
  const int q_ = nwg >> 3, r_ = nwg & 7;
  const int xcd = blockIdx.x & 7, bidx = blockIdx.x >> 3;
  const int bid = (xcd < r_ ? xcd * (q_ + 1) : r_ * (q_ + 1) + (xcd - r_) * q_) + bidx;
  const int e0 = bid * 64;

  if (tid < 64) {
    int idx = min(e0 + tid, N_EDGES - 1);
    sSrc[tid] = srcS[idx]; sDst[tid] = dstS[idx];
  }
  __syncthreads();                                              // B1

  const int wv = tid >> 6, lane = tid & 63, quad = lane >> 4, ln15 = lane & 15;

  // eattr A-fragments: LINEAR bf16 reads
  const int slotA = min(e0 + wv * 16 + ln15, N_EDGES - 1);
  short8v afr[2][2];
#pragma unroll
  for (int c = 0; c < 2; ++c)
#pragma unroll
    for (int ks = 0; ks < 2; ++ks)
      afr[c][ks] = *(const short8v*)&eattrS[(size_t)slotA * H + c * 64 + ks * 32 + quad * 8];

  // assemble XA[dst] + XB[src] into sM
#pragma unroll
  for (int i_ = 0; i_ < 4; ++i_) {
    int flat = tid + i_ * 256;
    int row = flat >> 4, sg = flat & 15;
    ushort8v a = *(const ushort8v*)&xab[(size_t)sDst[row] * 256 + sg * 8];
    ushort8v b = *(const ushort8v*)&xab[(size_t)sSrc[row] * 256 + 128 + sg * 8];
    ushort8v o;
#pragma unroll
    for (int j = 0; j < 8; ++j) o[j] = f2b(b2f(a[j]) + b2f(b[j]));
    *(ushort8v*)&sM[row * 136 + sg * 8] = o;
  }

  STAGE128(mW1t, 384, 256)                                      // W1c whole
  __syncthreads();                                              // B2

  f32x4 acc[8];
#pragma unroll
  for (int nt = 0; nt < 8; ++nt) acc[nt] = (f32x4){0.f, 0.f, 0.f, 0.f};

  // GEMM1c: eattr @ W1c (A in regs)
#pragma unroll
  for (int c = 0; c < 2; ++c)
#pragma unroll
    for (int ks = 0; ks < 2; ++ks) {
#pragma unroll
      for (int nt = 0; nt < 8; ++nt) {
        short8v bf = *(const short8v*)&sB[(nt * 16 + ln15) * 136 + c * 64 + ks * 32 + quad * 8];
        acc[nt] = __builtin_amdgcn_mfma_f32_16x16x32_bf16(afr[c][ks], bf, acc[nt], 0, 0, 0);
      }
    }

  // h1 = relu(acc + (XA+XB+mb1))
#pragma unroll
  for (int nt = 0; nt < 8; ++nt) {
    int col = nt * 16 + ln15;
#pragma unroll
    for (int r = 0; r < 4; ++r) {
      int row = wv * 16 + quad * 4 + r;
      float xv = b2f(sM[row * 136 + col]);
      sM[row * 136 + col] = f2b(fmaxf(acc[nt][r] + xv, 0.f));
      acc[nt][r] = 0.f;
    }
  }
  __syncthreads();                                              // B3

  STAGE128(mW2t, 128, 0)
  __syncthreads();                                              // B4

  MFMA_FULL(sM, acc)                                            // GEMM2: h1 @ W2
  __syncthreads();                                              // B5

  // m = acc + mb2 -> sM; stage aW1 h0 concurrently
#pragma unroll
  for (int nt = 0; nt < 8; ++nt) {
    int col = nt * 16 + ln15;
    float bb = mb2[col];
#pragma unroll
    for (int r = 0; r < 4; ++r) {
      int row = wv * 16 + quad * 4 + r;
      sM[row * 136 + col] = f2b(acc[nt][r] + bb);
    }
  }
  STAGE128(aW1t, 128, 0)
  __syncthreads();                                              // B6

  float wp0 = 0.f, wp1 = 0.f, wp2 = 0.f, wp3 = 0.f;
  {
#pragma unroll
    for (int nt = 0; nt < 8; ++nt) acc[nt] = (f32x4){0.f, 0.f, 0.f, 0.f};
    MFMA_FULL(sM, acc)
#pragma unroll
    for (int nt = 0; nt < 8; ++nt) {
      int col = nt * 16 + ln15;
      float bb = ab1[col], a2 = aW2[col];
      wp0 += fmaxf(acc[nt][0] + bb, 0.f) * a2;
      wp1 += fmaxf(acc[nt][1] + bb, 0.f) * a2;
      wp2 += fmaxf(acc[nt][2] + bb, 0.f) * a2;
      wp3 += fmaxf(acc[nt][3] + bb, 0.f) * a2;
    }
  }
  __syncthreads();                                              // B7
  STAGE128((aW1t + (size_t)128 * 128), 128, 0)
  __syncthreads();                                              // B8
  {
#pragma unroll
    for (int nt = 0; nt < 8; ++nt) acc[nt] = (f32x4){0.f, 0.f, 0.f, 0.f};
    MFMA_FULL(sM, acc)
#pragma unroll
    for (int nt = 0; nt < 8; ++nt) {
      int col = 128 + nt * 16 + ln15;
      float bb = ab1[col], a2 = aW2[col];
      wp0 += fmaxf(acc[nt][0] + bb, 0.f) * a2;
      wp1 += fmaxf(acc[nt][1] + bb, 0.f) * a2;
      wp2 += fmaxf(acc[nt][2] + bb, 0.f) * a2;
      wp3 += fmaxf(acc[nt][3] + bb, 0.f) * a2;
    }
  }
#pragma unroll
  for (int m = 1; m <= 8; m <<= 1) {
    wp0 += __shfl_xor(wp0, m, 64);
    wp1 += __shfl_xor(wp1, m, 64);
    wp2 += __shfl_xor(wp2, m, 64);
    wp3 += __shfl_xor(wp3, m, 64);
  }
  if (ln15 == 0) {
    float b2 = ab2[0];
    sW[wv * 16 + quad * 4 + 0] = wp0 + b2;
    sW[wv * 16 + quad * 4 + 1] = wp1 + b2;
    sW[wv * 16 + quad * 4 + 2] = wp2 + b2;
    sW[wv * 16 + quad * 4 + 3] = wp3 + b2;
  }

  // store m (sM stable since B6), coalesced 16B chunks
  if (do_m) {
#pragma unroll
    for (int i_ = 0; i_ < 4; ++i_) {
      int flat = tid + i_ * 256;
      int row = flat >> 4, sg = flat & 15;
      int slot = e0 + row;
      if (slot < N_EDGES)
        *(ushort8v*)&mS[(size_t)slot * H + sg * 8] =
            *(const ushort8v*)&sM[row * 136 + sg * 8];
    }
  }
  __syncthreads();                                              // B9
  if (tid < 64 && e0 + tid < N_EDGES) wS[e0 + tid] = sW[tid];
}

// ---------------- segmented reduce: 16 nodes/block, 16 lanes/node ----------------
// intraB[n] = bf16( (sum_m over CSR range) * invd[n] )  -- identical numerics to
// the previous k_node-side f2b(sum*iv).

__launch_bounds__(256, 8)
__global__ void k_seg(const unsigned short* __restrict__ mS,
                      const float* __restrict__ wS,
                      const int* __restrict__ srcS,
                      const float* __restrict__ pos,
                      const int* __restrict__ cursor,   // cursor[n] = exclusive end of node n
                      const float* __restrict__ invd,
                      unsigned short* __restrict__ intraB,  // [N][128] bf16 (pre-scaled)
                      float* __restrict__ pdelta,
                      int do_intra)
{
  const int tid = threadIdx.x;
  const int n = blockIdx.x * 16 + (tid >> 4);
  const int seg = tid & 15;
  if (n >= N_NODES) return;
  const int rs = (n == 0) ? 0 : cursor[n - 1];
  const int re = cursor[n];

  if (do_intra) {
    float a0=0.f,a1=0.f,a2=0.f,a3=0.f,a4=0.f,a5=0.f,a6=0.f,a7=0.f;
    for (int s = rs; s < re; ++s) {
      ushort8v v = *(const ushort8v*)&mS[(size_t)s * H + seg * 8];
      a0 += b2f(v[0]); a1 += b2f(v[1]); a2 += b2f(v[2]); a3 += b2f(v[3]);
      a4 += b2f(v[4]); a5 += b2f(v[5]); a6 += b2f(v[6]); a7 += b2f(v[7]);
    }
    float iv = invd[n];
    ushort8v o;
    o[0] = f2b(a0 * iv); o[1] = f2b(a1 * iv); o[2] = f2b(a2 * iv); o[3] = f2b(a3 * iv);
    o[4] = f2b(a4 * iv); o[5] = f2b(a5 * iv); o[6] = f2b(a6 * iv); o[7] = f2b(a7 * iv);
    *(ushort8v*)&intraB[(size_t)n * H + seg * 8] = o;
  }

  if (seg < 3) {
    const float px = pos[n * 3 + 0], py = pos[n * 3 + 1], pz = pos[n * 3 + 2];
    float a = 0.f;
    for (int s = rs; s < re; ++s) {
      int sn = srcS[s];
      float rx = pos[sn * 3 + 0] - px;
      float ry = pos[sn * 3 + 1] - py;
      float rz = pos[sn * 3 + 2] - pz;
      float dist = sqrtf(rx * rx + ry * ry + rz * rz);
      float rc = (seg == 0) ? rx : ((seg == 1) ? ry : rz);
      a += wS[s] * rc / dist;
    }
    pdelta[n * 3 + seg] = a;
  }
}

// ---------------- node kernel (R1-proven form; intra now bf16 pre-scaled) ----------------

__launch_bounds__(256, 3)
__global__ void k_node(const unsigned short* __restrict__ xb,
                       const unsigned short* __restrict__ intraB,
                       const float* __restrict__ invd,
                       const unsigned short* __restrict__ nW1t, const float* __restrict__ nb1,
                       const unsigned short* __restrict__ nW2t, const float* __restrict__ nb2,
                       const float* __restrict__ pos_in,
                       const float* __restrict__ pdelta,
                       unsigned short* __restrict__ xb_out,
                       float* __restrict__ pos_out,
                       int compute_x)
{
  __shared__ unsigned short sA[64 * 72];
  __shared__ unsigned short sB[128 * 72];
  __shared__ unsigned short sH[64 * 136];
  const int tid = threadIdx.x;
  const int n0 = blockIdx.x * 64;

  if (tid < 192) {
    int n = n0 + tid / 3, cc = tid % 3;
    if (n < N_NODES)
      pos_out[n * 3 + cc] = pos_in[n * 3 + cc] + pdelta[n * 3 + cc] * invd[n];
  }
  if (!compute_x) return;

  const int wv = tid >> 6, lane = tid & 63, quad = lane >> 4, ln15 = lane & 15;

  f32x4 xacc[8];
#pragma unroll
  for (int nt = 0; nt < 8; ++nt) xacc[nt] = (f32x4){0.f, 0.f, 0.f, 0.f};

  f32x4 acc[8];
  for (int h = 0; h < 2; ++h) {
#pragma unroll
    for (int nt = 0; nt < 8; ++nt) acc[nt] = (f32x4){0.f, 0.f, 0.f, 0.f};
    for (int c = 0; c < 4; ++c) {
#pragma unroll
      for (int i_ = 0; i_ < 2; ++i_) {
        int flat_ = tid + i_ * 256;
        int row = flat_ >> 3, seg = flat_ & 7;
        int n = min(n0 + row, N_NODES - 1);
        const unsigned short* src = (c < 2)
            ? &xb[(size_t)n * H + c * 64 + seg * 8]
            : &intraB[(size_t)n * H + (c - 2) * 64 + seg * 8];
        *(float4*)&sA[row * 72 + seg * 8] = *(const float4*)src;
      }
      STAGE_B(nW1t[((size_t)h * 128 + n) * 256 + c * 64 + seg * 8])
      __syncthreads();
      MFMA_STEP(sA, 72, 0, acc)
      __syncthreads();
    }
#pragma unroll
    for (int nt = 0; nt < 8; ++nt) {
      int col = nt * 16 + ln15;
      float bb = nb1[h * 128 + col];
#pragma unroll
      for (int r = 0; r < 4; ++r) {
        int row = wv * 16 + quad * 4 + r;
        sH[row * 136 + col] = f2b(fmaxf(acc[nt][r] + bb, 0.f));
      }
    }
    __syncthreads();
    for (int c2 = 0; c2 < 2; ++c2) {
      STAGE_B(nW2t[(size_t)n * 256 + h * 128 + c2 * 64 + seg * 8])
      __syncthreads();
      MFMA_STEP(sH, 136, c2 * 64, xacc)
      __syncthreads();
    }
  }
#pragma unroll
  for (int nt = 0; nt < 8; ++nt) {
    int col = nt * 16 + ln15;
    float bb = nb2[col];
#pragma unroll
    for (int r = 0; r < 4; ++r) {
      int row = n0 + wv * 16 + quad * 4 + r;
      if (row < N_NODES)
        xb_out[(size_t)row * H + col] = f2b(xacc[nt][r] + bb);
    }
  }
}

extern "C" void kernel_launch(void* const* d_in, const int* in_sizes, int n_in,
                              void* d_out, int out_size, void* d_ws, size_t ws_size,
                              hipStream_t stream) {
  const float* x0    = (const float*)d_in[0];
  const int*   eidx  = (const int*)d_in[1];
  const float* eattr = (const float*)d_in[2];
  const float* pos0  = (const float*)d_in[3];
  const float* mW1 = (const float*)d_in[4];
  const float* mb1 = (const float*)d_in[5];
  const float* mW2 = (const float*)d_in[6];
  const float* mb2 = (const float*)d_in[7];
  const float* aW1 = (const float*)d_in[8];
  const float* ab1 = (const float*)d_in[9];
  const float* aW2 = (const float*)d_in[10];
  const float* ab2 = (const float*)d_in[11];
  const float* nW1 = (const float*)d_in[12];
  const float* nb1 = (const float*)d_in[13];
  const float* nW2 = (const float*)d_in[14];
  const float* nb2 = (const float*)d_in[15];
  const int* srcI = eidx;
  const int* dstI = eidx + N_EDGES;

  char* wsb = (char*)d_ws;
  int*   degC    = (int*)wsb;                     wsb += (size_t)N_NODES * 4;
  int*   cursor  = (int*)wsb;                     wsb += (size_t)N_NODES * 4;
  int*   chunkS  = (int*)wsb;                     wsb += 256 * 4;
  int*   sorted  = (int*)wsb;                     wsb += (size_t)N_EDGES * 4;
  float* invd    = (float*)wsb;                   wsb += (size_t)N_NODES * 4;
  float* pdelta  = (float*)wsb;                   wsb += (size_t)3 * N_NODES * 4;
  float* pos_a   = (float*)wsb;                   wsb += (size_t)3 * N_NODES * 4;
  float* pos_b   = (float*)wsb;                   wsb += (size_t)3 * N_NODES * 4;
  unsigned short* intraB = (unsigned short*)wsb;  wsb += (size_t)N_NODES * H * 2;
  unsigned short* xb0  = (unsigned short*)wsb;    wsb += (size_t)N_NODES * H * 2;
  unsigned short* xb_a = (unsigned short*)wsb;    wsb += (size_t)N_NODES * H * 2;
  unsigned short* xb_b = (unsigned short*)wsb;    wsb += (size_t)N_NODES * H * 2;
  unsigned short* xabW = (unsigned short*)wsb;    wsb += (size_t)N_NODES * 256 * 2;
  unsigned short* eattrS = (unsigned short*)wsb;  wsb += (size_t)N_EDGES * H * 2;
  unsigned short* mS   = (unsigned short*)wsb;    wsb += (size_t)N_EDGES * H * 2;
  int*   srcS    = (int*)wsb;                     wsb += (size_t)N_EDGES * 4;
  int*   dstS    = (int*)wsb;                     wsb += (size_t)N_EDGES * 4;
  float* wS      = (float*)wsb;                   wsb += (size_t)N_EDGES * 4;
  unsigned short* mW1t = (unsigned short*)wsb;    wsb += (size_t)NL * 128 * 384 * 2;
  unsigned short* mW2t = (unsigned short*)wsb;    wsb += (size_t)NL * 128 * 128 * 2;
  unsigned short* aW1t = (unsigned short*)wsb;    wsb += (size_t)NL * 256 * 128 * 2;
  unsigned short* nW1t = (unsigned short*)wsb;    wsb += (size_t)NL * 256 * 256 * 2;
  unsigned short* nW2t = (unsigned short*)wsb;    wsb += (size_t)NL * 128 * 256 * 2;

  // counting sort of edges by dst (every launch; ws is re-poisoned)
  hipMemsetAsync(degC, 0, N_NODES * sizeof(int), stream);
  k_deg_i<<<(N_EDGES + 255) / 256, 256, 0, stream>>>(dstI, degC);
  k_inv<<<(N_NODES + 255) / 256, 256, 0, stream>>>(degC, invd);
  k_scan1<<<NCHUNK, SCAN_B, 0, stream>>>(degC, cursor, chunkS);
  k_scan2<<<1, SCAN_B, 0, stream>>>(chunkS);
  k_scan3<<<NCHUNK, SCAN_B, 0, stream>>>(cursor, chunkS);
  k_scatter_sort<<<(N_EDGES + 255) / 256, 256, 0, stream>>>(dstI, cursor, sorted);
  // NOTE: after k_scatter_sort, cursor[n] == exclusive end of node n's slot range

  // one-time: permute eattr/src/dst into dst-sorted slot order (bf16)
  k_perm<<<(N_EDGES * 16 + 255) / 256, 256, 0, stream>>>(
      eattr, sorted, srcI, dstI, eattrS, srcS, dstS);

  // bf16 conversions
  {
    int n4 = N_NODES * H / 4;
    k_cvt_x<<<(n4 + 255) / 256, 256, 0, stream>>>(x0, xb0, n4);
    int t1 = NL * 384 * 128;
    k_cvt_wt<<<(t1 + 255) / 256, 256, 0, stream>>>(mW1, mW1t, 384, 128, t1);
    int t2 = NL * 128 * 128;
    k_cvt_wt<<<(t2 + 255) / 256, 256, 0, stream>>>(mW2, mW2t, 128, 128, t2);
    int t3 = NL * 128 * 256;
    k_cvt_wt<<<(t3 + 255) / 256, 256, 0, stream>>>(aW1, aW1t, 128, 256, t3);
    int t4 = NL * 256 * 256;
    k_cvt_wt<<<(t4 + 255) / 256, 256, 0, stream>>>(nW1, nW1t, 256, 256, t4);
    int t5 = NL * 256 * 128;
    k_cvt_wt<<<(t5 + 255) / 256, 256, 0, stream>>>(nW2, nW2t, 256, 128, t5);
  }

  const unsigned short* xc = xb0;
  const float* pc = pos0;
  float* pos_out_final = (float*)d_out;

  for (int l = 0; l < NL; ++l) {
    int last = (l == NL - 1);

    k_xab<<<(N_NODES + 63) / 64, 256, 0, stream>>>(
        xc, mW1t + (size_t)l * 128 * 384, mb1 + (size_t)l * 128, xabW);

    k_edge_m<<<(N_EDGES + 63) / 64, 256, 0, stream>>>(
        xabW, eattrS, srcS, dstS,
        mW1t + (size_t)l * 128 * 384,
        mW2t + (size_t)l * 128 * 128, mb2 + (size_t)l * 128,
        aW1t + (size_t)l * 256 * 128, ab1 + (size_t)l * 256,
        aW2 + (size_t)l * 256, ab2 + l,
        mS, wS, last ? 0 : 1);

    k_seg<<<(N_NODES + 15) / 16, 256, 0, stream>>>(
        mS, wS, srcS, pc, cursor, invd, intraB, pdelta, last ? 0 : 1);

    float* pn = last ? pos_out_final : (l == 0 ? pos_a : pos_b);
    unsigned short* xn = (l == 0) ? xb_a : xb_b;
    k_node<<<(N_NODES + 63) / 64, 256, 0, stream>>>(
        xc, intraB, invd,
        nW1t + (size_t)l * 256 * 256, nb1 + (size_t)l * 256,
        nW2t + (size_t)l * 128 * 256, nb2 + (size_t)l * 128,
        pc, pdelta, xn, pn, last ? 0 : 1);

    xc = xn;
    pc = pn;
  }
}